// Round 8
// baseline (253.385 us; speedup 1.0000x reference)
//
#include <hip/hip_runtime.h>

#define T_LEN 800
#define B_SZ  16
#define D_IN  80
#define CCH   256
#define OUT_CH 222
#define HOPSZ 256
#define WINSZ 512
#define ZLEN  (T_LEN*HOPSZ)   // 204800
#define CSTRIDE 256           // ccep row stride ([t][co] layout)
#define TPAD 816              // padded time stride for [b][c][t] layout (halo at 0 and 801)

#define PHI(i) ((i) + ((i)>>3))

__device__ __forceinline__ float2 cmul(float2 a, float2 b){
    return make_float2(a.x*b.x - a.y*b.y, a.x*b.y + a.y*b.x);
}

// -------- weight transpose to float4 [ci][co]; also zero halo columns of h1/h2 --------
__global__ __launch_bounds__(256) void k_wtrans(const float* __restrict__ W1,
                                                const float* __restrict__ W2,
                                                const float* __restrict__ W3,
                                                const float* __restrict__ W4,
                                                float4* __restrict__ w1t,
                                                float4* __restrict__ w2t,
                                                float4* __restrict__ w3t,
                                                float4* __restrict__ w4t,
                                                float* __restrict__ h1,
                                                float* __restrict__ h2){
    const int i = blockIdx.x*256 + threadIdx.x;
    switch (blockIdx.y){
    case 0: if (i < 80*256){
        int ci = i >> 8, co = i & 255;
        const float* s = &W1[(co*80 + ci)*3];
        w1t[i] = make_float4(s[0], s[1], s[2], 0.f);
    } break;
    case 1: if (i < 32*256){
        int cil = i >> 8, co = i & 255;
        const float* s = &W2[(co*32 + cil)*3];
        w2t[i] = make_float4(s[0], s[1], s[2], 0.f);
    } break;
    case 2: if (i < 32*256){
        int cil = i >> 8, co = i & 255;
        const float* s = &W3[(co*32 + cil)*3];
        w3t[i] = make_float4(s[0], s[1], s[2], 0.f);
    } break;
    case 3: if (i < 256*256){
        int ci = i >> 8, co = i & 255;
        if (co < OUT_CH){
            const float* s = &W4[(co*256 + ci)*3];
            w4t[i] = make_float4(s[0], s[1], s[2], 0.f);
        } else {
            w4t[i] = make_float4(0.f, 0.f, 0.f, 0.f);
        }
    } break;
    default: if (i < B_SZ*CCH*4){
        int rc  = i >> 2;               // b*256+c
        float* buf = (i & 1) ? h1 : h2;
        int idx = (i & 2) ? 0 : 801;    // halo positions (t=-1 and t=800)
        buf[(size_t)rc*TPAD + idx] = 0.f;
    } break;
    }
}

// -------- conv1: x (B,T,80) -> h1 [b][c][TPAD], relu --------
__global__ __launch_bounds__(256) void k_conv1(const float* __restrict__ x,
                                               const float4* __restrict__ Wt,
                                               const float* __restrict__ bias,
                                               float* __restrict__ out){
    __shared__ __align__(16) float xs[80*20];
    const int t0 = blockIdx.x * 16;
    const int b  = blockIdx.y;
    const int tid = threadIdx.x;
    const int co = tid;
    for (int i = tid; i < 80*18; i += 256){
        int tt = i / 80, ci = i - tt*80;
        int t = t0 - 1 + tt;
        xs[ci*20 + tt] = (t >= 0 && t < T_LEN) ? x[(b*T_LEN + t)*D_IN + ci] : 0.f;
    }
    __syncthreads();
    float acc[16];
    float bv = bias[co];
    #pragma unroll
    for (int t = 0; t < 16; ++t) acc[t] = bv;
    const float4* wp = Wt + co;
    float4 w = *wp;
    for (int ci = 0; ci < 80; ++ci){
        wp += 256;
        float4 wn = *wp;   // prefetch; overrun lands in adjacent weight buffer, unused
        const float* xp = &xs[ci*20];
        float4 v0 = *(const float4*)(xp);
        float4 v1 = *(const float4*)(xp + 4);
        float4 v2 = *(const float4*)(xp + 8);
        float4 v3 = *(const float4*)(xp + 12);
        float2 v4 = *(const float2*)(xp + 16);
        float xr[18] = {v0.x,v0.y,v0.z,v0.w, v1.x,v1.y,v1.z,v1.w,
                        v2.x,v2.y,v2.z,v2.w, v3.x,v3.y,v3.z,v3.w, v4.x,v4.y};
        #pragma unroll
        for (int t = 0; t < 16; ++t){
            acc[t] = fmaf(xr[t],   w.x, acc[t]);
            acc[t] = fmaf(xr[t+1], w.y, acc[t]);
            acc[t] = fmaf(xr[t+2], w.z, acc[t]);
        }
        w = wn;
    }
    float* orow = out + ((size_t)b*CCH + co)*TPAD + t0 + 1;
    #pragma unroll
    for (int t = 0; t < 16; ++t) orow[t] = fmaxf(acc[t], 0.f);
}

// -------- grouped conv (groups=8): h[b][c][TPAD] -> h[b][c][TPAD], relu --------
__global__ __launch_bounds__(256) void k_convg(const float* __restrict__ in,
                                               const float4* __restrict__ Wt,
                                               const float* __restrict__ bias,
                                               float* __restrict__ out){
    __shared__ __align__(16) float hs[256*20];
    const int t0 = blockIdx.x * 16;
    const int b  = blockIdx.y;
    const int tid = threadIdx.x;
    const int co = tid;
    const int gbase = (co >> 5) << 5;
    // stage: halo already zeroed in the buffer, no bounds checks
    for (int i = tid; i < 256*18; i += 256){
        int ci = i / 18, tt = i - ci*18;
        hs[ci*20 + tt] = in[((size_t)b*CCH + ci)*TPAD + t0 + tt];
    }
    __syncthreads();
    float acc[16];
    float bv = bias[co];
    #pragma unroll
    for (int t = 0; t < 16; ++t) acc[t] = bv;
    const float4* wp = Wt + co;
    float4 w = *wp;
    for (int cil = 0; cil < 32; ++cil){
        wp += 256;
        float4 wn = *wp;
        const float* xp = &hs[(gbase + cil)*20];
        float4 v0 = *(const float4*)(xp);
        float4 v1 = *(const float4*)(xp + 4);
        float4 v2 = *(const float4*)(xp + 8);
        float4 v3 = *(const float4*)(xp + 12);
        float2 v4 = *(const float2*)(xp + 16);
        float xr[18] = {v0.x,v0.y,v0.z,v0.w, v1.x,v1.y,v1.z,v1.w,
                        v2.x,v2.y,v2.z,v2.w, v3.x,v3.y,v3.z,v3.w, v4.x,v4.y};
        #pragma unroll
        for (int t = 0; t < 16; ++t){
            acc[t] = fmaf(xr[t],   w.x, acc[t]);
            acc[t] = fmaf(xr[t+1], w.y, acc[t]);
            acc[t] = fmaf(xr[t+2], w.z, acc[t]);
        }
        w = wn;
    }
    float* orow = out + ((size_t)b*CCH + co)*TPAD + t0 + 1;
    #pragma unroll
    for (int t = 0; t < 16; ++t) orow[t] = fmaxf(acc[t], 0.f);
}

// -------- conv4: h1 [b][c][TPAD] -> ccep [t][co]; NO LDS, uniform x rows --------
__global__ __launch_bounds__(256) void k_conv4(const float* __restrict__ in,
                                               const float4* __restrict__ Wt,
                                               const float* __restrict__ bias,
                                               float* __restrict__ ccep){
    const int t0 = blockIdx.x * 16;
    const int b  = blockIdx.y;
    const int co = threadIdx.x;
    float acc[16];
    float bv = (co < OUT_CH) ? bias[co] : 0.f;
    #pragma unroll
    for (int t = 0; t < 16; ++t) acc[t] = bv;
    const float* rp = in + ((size_t)b*CCH)*TPAD + t0;   // ci=0 window start
    const float4* wp = Wt + co;
    float4 w0 = *wp;
    float xa[18], xb[18];
    #pragma unroll
    for (int k = 0; k < 18; ++k) xa[k] = rp[k];
    #pragma unroll 1
    for (int ci = 0; ci < 256; ci += 2){
        // load row ci+1 (pipeline); overruns on last iter stay in-bounds of ws
        const float* rp1 = rp + TPAD;
        #pragma unroll
        for (int k = 0; k < 18; ++k) xb[k] = rp1[k];
        float4 w1 = wp[256];
        #pragma unroll
        for (int t = 0; t < 16; ++t){
            acc[t] = fmaf(xa[t],   w0.x, acc[t]);
            acc[t] = fmaf(xa[t+1], w0.y, acc[t]);
            acc[t] = fmaf(xa[t+2], w0.z, acc[t]);
        }
        rp += 2*TPAD;
        #pragma unroll
        for (int k = 0; k < 18; ++k) xa[k] = rp[k];     // row ci+2
        float4 w2 = wp[512];
        wp += 512;
        #pragma unroll
        for (int t = 0; t < 16; ++t){
            acc[t] = fmaf(xb[t],   w1.x, acc[t]);
            acc[t] = fmaf(xb[t+1], w1.y, acc[t]);
            acc[t] = fmaf(xb[t+2], w1.z, acc[t]);
        }
        w0 = w2;
    }
    float q = (co < 111) ? (float)(111 - co) : (float)(co - 110);
    float invq = 1.0f / q;
    #pragma unroll
    for (int t = 0; t < 16; ++t)
        ccep[(b*T_LEN + t0 + t)*CSTRIDE + co] = acc[t] * invq;
}

// -------- radix-4 Stockham stage --------
template<int Ns, bool INV>
__device__ __forceinline__ void r4stage(const float2* __restrict__ src,
                                        float2* __restrict__ dst,
                                        const float2* __restrict__ Wt,
                                        int j){
    const int jm = j & (Ns - 1);
    float2 v0 = src[PHI(j)];
    float2 v1 = src[PHI(j + 256)];
    float2 v2 = src[PHI(j + 512)];
    float2 v3 = src[PHI(j + 768)];
    if (Ns > 1){
        float2 w1 = Wt[PHI(jm * (256 / Ns))];
        if (INV) w1.y = -w1.y;
        float2 w2 = cmul(w1, w1);
        float2 w3 = cmul(w2, w1);
        v1 = cmul(v1, w1);
        v2 = cmul(v2, w2);
        v3 = cmul(v3, w3);
    }
    float2 t0 = make_float2(v0.x + v2.x, v0.y + v2.y);
    float2 t1 = make_float2(v0.x - v2.x, v0.y - v2.y);
    float2 t2 = make_float2(v1.x + v3.x, v1.y + v3.y);
    float2 t3 = make_float2(v1.x - v3.x, v1.y - v3.y);
    float2 o0 = make_float2(t0.x + t2.x, t0.y + t2.y);
    float2 o2 = make_float2(t0.x - t2.x, t0.y - t2.y);
    float2 o1, o3;
    if (!INV){
        o1 = make_float2(t1.x + t3.y, t1.y - t3.x);
        o3 = make_float2(t1.x - t3.y, t1.y + t3.x);
    } else {
        o1 = make_float2(t1.x - t3.y, t1.y + t3.x);
        o3 = make_float2(t1.x + t3.y, t1.y - t3.x);
    }
    const int base = ((j - jm) << 2) + jm;
    dst[PHI(base)]          = o0;
    dst[PHI(base + Ns)]     = o1;
    dst[PHI(base + 2*Ns)]   = o2;
    dst[PHI(base + 3*Ns)]   = o3;
}

// -------- per-(b,t): packed FFT(ccep,frame) -> G = conj(F)*H -> IFFT -> window --------
__global__ __launch_bounds__(256) void k_filter(const float* __restrict__ ccep,
                                                const float* __restrict__ z,
                                                float* __restrict__ zw){
    __shared__ __align__(16) float2 A[1152];
    __shared__ __align__(16) float2 Bb[1152];
    __shared__ __align__(16) float2 Wt[288];
    const int t = blockIdx.x;
    const int b = blockIdx.y;
    const int tid = threadIdx.x;
    const float PI2 = 6.283185307179586f;

    {
        float s, c;
        __sincosf(-PI2 * (float)tid * (1.0f/1024.0f), &s, &c);
        Wt[PHI(tid)] = make_float2(c, s);
    }
    const float* crow = &ccep[(b*T_LEN + t)*CSTRIDE];
    #pragma unroll
    for (int r = 0; r < 4; ++r){
        int i = tid + (r << 8);
        float av = (i >= 401 && i < 623) ? crow[i - 401] : 0.f;
        float fv = 0.f;
        if (i < 512){
            int zi = t*HOPSZ + i - 255;
            fv = (zi >= 0 && zi < ZLEN) ? z[b*ZLEN + zi] : 0.f;
        }
        A[PHI(i)] = make_float2(av, fv);
    }
    __syncthreads();

    r4stage<1,  false>(A,  Bb, Wt, tid); __syncthreads();
    r4stage<4,  false>(Bb, A,  Wt, tid); __syncthreads();
    r4stage<16, false>(A,  Bb, Wt, tid); __syncthreads();
    r4stage<64, false>(Bb, A,  Wt, tid); __syncthreads();
    r4stage<256,false>(A,  Bb, Wt, tid); __syncthreads();

    const float LOG2_10_DIV10 = 0.33219280948873623f;
    #pragma unroll
    for (int r = 0; r < 4; ++r){
        int i = tid + (r << 8);
        float2 P = Bb[PHI(i)];
        float2 Q = Bb[PHI((1024 - i) & 1023)];
        float Are = 0.5f * (P.x + Q.x);
        float Aim = 0.5f * (P.y - Q.y);
        float Fx  = 0.5f * (P.y + Q.y);
        float Fy  = 0.5f * (Q.x - P.x);
        float mag = exp2f(Are * LOG2_10_DIV10) * (1.0f/1024.0f);
        float s, c;
        sincosf(Aim, &s, &c);
        float Hx = mag * c, Hy = mag * s;
        A[PHI(i)] = make_float2(Fx*Hx + Fy*Hy, Fx*Hy - Fy*Hx);
    }
    __syncthreads();

    r4stage<1,  true>(A,  Bb, Wt, tid); __syncthreads();
    r4stage<4,  true>(Bb, A,  Wt, tid); __syncthreads();
    r4stage<16, true>(A,  Bb, Wt, tid); __syncthreads();
    r4stage<64, true>(Bb, A,  Wt, tid); __syncthreads();
    r4stage<256,true>(A,  Bb, Wt, tid); __syncthreads();

    float* zrow = &zw[(size_t)(b*T_LEN + t)*512];
    #pragma unroll
    for (int r = 0; r < 2; ++r){
        int n = tid + (r << 8);
        float yv = Bb[PHI(511 - n)].x;
        float wv = 0.5f * (1.0f - __cosf(PI2 * (float)n * (1.0f/512.0f)));
        zrow[n] = yv * wv;
    }
}

// -------- OLA + clip --------
__global__ __launch_bounds__(256) void k_ola(const float* __restrict__ zw,
                                             float* __restrict__ out){
    const int t = blockIdx.x;
    const int b = blockIdx.y;
    const int h = threadIdx.x;
    const int tm = (t + T_LEN - 1) % T_LEN;
    float v = zw[(size_t)(b*T_LEN + t)*512 + h]
            + zw[(size_t)(b*T_LEN + tm)*512 + 256 + h];
    v = fminf(fmaxf(v, -1.0f), 1.0f);
    out[(size_t)b*ZLEN + t*HOPSZ + h] = v;
}

extern "C" void kernel_launch(void* const* d_in, const int* in_sizes, int n_in,
                              void* d_out, int out_size, void* d_ws, size_t ws_size,
                              hipStream_t stream){
    const float* x  = (const float*)d_in[0];
    const float* z  = (const float*)d_in[1];
    const float* W1 = (const float*)d_in[2];
    const float* b1 = (const float*)d_in[3];
    const float* W2 = (const float*)d_in[4];
    const float* b2 = (const float*)d_in[5];
    const float* W3 = (const float*)d_in[6];
    const float* b3 = (const float*)d_in[7];
    const float* W4 = (const float*)d_in[8];
    const float* b4 = (const float*)d_in[9];
    float* out = (float*)d_out;
    float* ws  = (float*)d_ws;

    // layout (floats):
    float* h1   = ws;                         // [16][256][816] = 3,342,336
    float* h2   = ws + 3342336;               // [16][256][816] = 3,342,336
    float* ccep = h2;                         // overlays h2 (h2 dead after conv3): 12800*256
    float* zwb  = ws + 6684672;               // 6,553,600  (total 13,238,272 fl = 53.0 MB)
    // transposed float4 weights live in the FRONT of zwb (read only by convs,
    // overwritten later by k_filter — stream-ordered, safe)
    float4* w1t = (float4*)(zwb);             // 20480 f4
    float4* w2t = (float4*)(zwb + 81920);     //  8192 f4
    float4* w3t = (float4*)(zwb + 114688);    //  8192 f4
    float4* w4t = (float4*)(zwb + 147456);    // 65536 f4 (ends @ zwb+409600 floats)

    dim3 blk(256);
    dim3 gwt(256, 5);
    dim3 gconv(T_LEN/16, B_SZ);               // (50,16)
    dim3 gf(T_LEN, B_SZ);                     // (800,16)

    k_wtrans<<<gwt, blk, 0, stream>>>(W1, W2, W3, W4, w1t, w2t, w3t, w4t, h1, h2);
    k_conv1<<<gconv, blk, 0, stream>>>(x, w1t, b1, h1);
    k_convg<<<gconv, blk, 0, stream>>>(h1, w2t, b2, h2);
    k_convg<<<gconv, blk, 0, stream>>>(h2, w3t, b3, h1);
    k_conv4<<<gconv, blk, 0, stream>>>(h1, w4t, b4, ccep);
    k_filter<<<gf, blk, 0, stream>>>(ccep, z, zwb);
    k_ola<<<gf, blk, 0, stream>>>(zwb, out);
}

// Round 9
// 252.318 us; speedup vs baseline: 1.0042x; 1.0042x over previous
//
#include <hip/hip_runtime.h>

#define T_LEN 800
#define B_SZ  16
#define D_IN  80
#define CCH   256
#define OUT_CH 222
#define HOPSZ 256
#define WINSZ 512
#define ZLEN  (T_LEN*HOPSZ)   // 204800
#define CSTRIDE 256           // ccep row stride ([t][co] layout)

#define PHI(i) ((i) + ((i)>>3))

__device__ __forceinline__ float2 cmul(float2 a, float2 b){
    return make_float2(a.x*b.x - a.y*b.y, a.x*b.y + a.y*b.x);
}

// -------- weight transpose into float4 [ci][co] = (w0,w1,w2,0) --------
__global__ __launch_bounds__(256) void k_wtrans(const float* __restrict__ W1,
                                                const float* __restrict__ W2,
                                                const float* __restrict__ W3,
                                                const float* __restrict__ W4,
                                                float4* __restrict__ w1t,
                                                float4* __restrict__ w2t,
                                                float4* __restrict__ w3t,
                                                float4* __restrict__ w4t){
    const int i = blockIdx.x*256 + threadIdx.x;
    switch (blockIdx.y){
    case 0: if (i < 80*256){
        int ci = i >> 8, co = i & 255;
        const float* s = &W1[(co*80 + ci)*3];
        w1t[i] = make_float4(s[0], s[1], s[2], 0.f);
    } break;
    case 1: if (i < 32*256){
        int cil = i >> 8, co = i & 255;
        const float* s = &W2[(co*32 + cil)*3];
        w2t[i] = make_float4(s[0], s[1], s[2], 0.f);
    } break;
    case 2: if (i < 32*256){
        int cil = i >> 8, co = i & 255;
        const float* s = &W3[(co*32 + cil)*3];
        w3t[i] = make_float4(s[0], s[1], s[2], 0.f);
    } break;
    default: if (i < 256*256){
        int ci = i >> 8, co = i & 255;
        if (co < OUT_CH){
            const float* s = &W4[(co*256 + ci)*3];
            w4t[i] = make_float4(s[0], s[1], s[2], 0.f);
        } else {
            w4t[i] = make_float4(0.f, 0.f, 0.f, 0.f);
        }
    } break;
    }
}

// -------- conv1: x (B,T,80) -> h1 (B,T,256) [t][c], relu --------
__global__ __launch_bounds__(256) void k_conv1(const float* __restrict__ x,
                                               const float4* __restrict__ Wt,
                                               const float* __restrict__ bias,
                                               float* __restrict__ out){
    __shared__ __align__(16) float xs[80*20];
    const int t0 = blockIdx.x * 16;
    const int b  = blockIdx.y;
    const int tid = threadIdx.x;
    const int co = tid;
    for (int i = tid; i < 80*18; i += 256){
        int tt = i / 80, ci = i - tt*80;
        int t = t0 - 1 + tt;
        xs[ci*20 + tt] = (t >= 0 && t < T_LEN) ? x[(b*T_LEN + t)*D_IN + ci] : 0.f;
    }
    __syncthreads();
    float acc[16];
    float bv = bias[co];
    #pragma unroll
    for (int t = 0; t < 16; ++t) acc[t] = bv;
    const float4* wp = Wt + co;
    float4 w = *wp;
    for (int ci = 0; ci < 80; ++ci){
        wp += 256;
        float4 wn = *wp;   // prefetch; overrun lands in adjacent weight buffer, unused
        const float* xp = &xs[ci*20];
        float4 v0 = *(const float4*)(xp);
        float4 v1 = *(const float4*)(xp + 4);
        float4 v2 = *(const float4*)(xp + 8);
        float4 v3 = *(const float4*)(xp + 12);
        float2 v4 = *(const float2*)(xp + 16);
        float xr[18] = {v0.x,v0.y,v0.z,v0.w, v1.x,v1.y,v1.z,v1.w,
                        v2.x,v2.y,v2.z,v2.w, v3.x,v3.y,v3.z,v3.w, v4.x,v4.y};
        #pragma unroll
        for (int t = 0; t < 16; ++t){
            acc[t] = fmaf(xr[t],   w.x, acc[t]);
            acc[t] = fmaf(xr[t+1], w.y, acc[t]);
            acc[t] = fmaf(xr[t+2], w.z, acc[t]);
        }
        w = wn;
    }
    #pragma unroll
    for (int t = 0; t < 16; ++t)
        out[(b*T_LEN + t0 + t)*CCH + co] = fmaxf(acc[t], 0.f);
}

// -------- grouped conv (256->256, groups=8), relu --------
__global__ __launch_bounds__(256) void k_convg(const float* __restrict__ in,
                                               const float4* __restrict__ Wt,
                                               const float* __restrict__ bias,
                                               float* __restrict__ out){
    __shared__ __align__(16) float hs[256*20];
    const int t0 = blockIdx.x * 16;
    const int b  = blockIdx.y;
    const int tid = threadIdx.x;
    const int co = tid;
    const int gbase = (co >> 5) << 5;
    for (int i = tid; i < 256*18; i += 256){
        int tt = i >> 8, ci = i & 255;
        int t = t0 - 1 + tt;
        hs[ci*20 + tt] = (t >= 0 && t < T_LEN) ? in[(b*T_LEN + t)*CCH + ci] : 0.f;
    }
    __syncthreads();
    float acc[16];
    float bv = bias[co];
    #pragma unroll
    for (int t = 0; t < 16; ++t) acc[t] = bv;
    const float4* wp = Wt + co;
    float4 w = *wp;
    for (int cil = 0; cil < 32; ++cil){
        wp += 256;
        float4 wn = *wp;
        const float* xp = &hs[(gbase + cil)*20];
        float4 v0 = *(const float4*)(xp);
        float4 v1 = *(const float4*)(xp + 4);
        float4 v2 = *(const float4*)(xp + 8);
        float4 v3 = *(const float4*)(xp + 12);
        float2 v4 = *(const float2*)(xp + 16);
        float xr[18] = {v0.x,v0.y,v0.z,v0.w, v1.x,v1.y,v1.z,v1.w,
                        v2.x,v2.y,v2.z,v2.w, v3.x,v3.y,v3.z,v3.w, v4.x,v4.y};
        #pragma unroll
        for (int t = 0; t < 16; ++t){
            acc[t] = fmaf(xr[t],   w.x, acc[t]);
            acc[t] = fmaf(xr[t+1], w.y, acc[t]);
            acc[t] = fmaf(xr[t+2], w.z, acc[t]);
        }
        w = wn;
    }
    #pragma unroll
    for (int t = 0; t < 16; ++t)
        out[(b*T_LEN + t0 + t)*CCH + co] = fmaxf(acc[t], 0.f);
}

// -------- conv4: 512 threads (co=tid&255, t-half=tid>>8), grid stays 800 --------
// 8 waves/block -> 25 waves/CU; weight stream read ONCE per block (t-span 16)
__global__ __launch_bounds__(512) void k_conv4(const float* __restrict__ in,
                                               const float4* __restrict__ Wt,
                                               const float* __restrict__ bias,
                                               float* __restrict__ ccep){
    __shared__ __align__(16) float hs[256*20];
    const int t0 = blockIdx.x * 16;
    const int b  = blockIdx.y;
    const int tid = threadIdx.x;
    const int co   = tid & 255;
    const int toff = (tid >> 8) << 3;   // 0 or 8
    for (int i = tid; i < 256*18; i += 512){
        int tt = i >> 8, ci = i & 255;
        int t = t0 - 1 + tt;
        hs[ci*20 + tt] = (t >= 0 && t < T_LEN) ? in[(b*T_LEN + t)*CCH + ci] : 0.f;
    }
    __syncthreads();
    float acc[8];
    float bv = (co < OUT_CH) ? bias[co] : 0.f;
    #pragma unroll
    for (int t = 0; t < 8; ++t) acc[t] = bv;
    const float4* wp = Wt + co;
    float4 wa = wp[0];
    float4 wb = wp[256];
    #pragma unroll 1
    for (int ci = 0; ci < 256; ci += 2){
        float4 wn0 = wp[512];            // depth-2 prefetch (overrun benign)
        float4 wn1 = wp[768];
        wp += 512;
        const float* xp0 = &hs[ci*20 + toff];
        {
            float4 v0 = *(const float4*)(xp0);
            float4 v1 = *(const float4*)(xp0 + 4);
            float2 v2 = *(const float2*)(xp0 + 8);
            float xr[10] = {v0.x,v0.y,v0.z,v0.w, v1.x,v1.y,v1.z,v1.w, v2.x,v2.y};
            #pragma unroll
            for (int t = 0; t < 8; ++t){
                acc[t] = fmaf(xr[t],   wa.x, acc[t]);
                acc[t] = fmaf(xr[t+1], wa.y, acc[t]);
                acc[t] = fmaf(xr[t+2], wa.z, acc[t]);
            }
        }
        {
            const float* xp1 = xp0 + 20;
            float4 v0 = *(const float4*)(xp1);
            float4 v1 = *(const float4*)(xp1 + 4);
            float2 v2 = *(const float2*)(xp1 + 8);
            float xr[10] = {v0.x,v0.y,v0.z,v0.w, v1.x,v1.y,v1.z,v1.w, v2.x,v2.y};
            #pragma unroll
            for (int t = 0; t < 8; ++t){
                acc[t] = fmaf(xr[t],   wb.x, acc[t]);
                acc[t] = fmaf(xr[t+1], wb.y, acc[t]);
                acc[t] = fmaf(xr[t+2], wb.z, acc[t]);
            }
        }
        wa = wn0;
        wb = wn1;
    }
    float q = (co < 111) ? (float)(111 - co) : (float)(co - 110);
    float invq = 1.0f / q;
    #pragma unroll
    for (int t = 0; t < 8; ++t)
        ccep[(b*T_LEN + t0 + toff + t)*CSTRIDE + co] = acc[t] * invq;
}

// -------- radix-4 Stockham stage --------
template<int Ns, bool INV>
__device__ __forceinline__ void r4stage(const float2* __restrict__ src,
                                        float2* __restrict__ dst,
                                        const float2* __restrict__ Wt,
                                        int j){
    const int jm = j & (Ns - 1);
    float2 v0 = src[PHI(j)];
    float2 v1 = src[PHI(j + 256)];
    float2 v2 = src[PHI(j + 512)];
    float2 v3 = src[PHI(j + 768)];
    if (Ns > 1){
        float2 w1 = Wt[PHI(jm * (256 / Ns))];
        if (INV) w1.y = -w1.y;
        float2 w2 = cmul(w1, w1);
        float2 w3 = cmul(w2, w1);
        v1 = cmul(v1, w1);
        v2 = cmul(v2, w2);
        v3 = cmul(v3, w3);
    }
    float2 t0 = make_float2(v0.x + v2.x, v0.y + v2.y);
    float2 t1 = make_float2(v0.x - v2.x, v0.y - v2.y);
    float2 t2 = make_float2(v1.x + v3.x, v1.y + v3.y);
    float2 t3 = make_float2(v1.x - v3.x, v1.y - v3.y);
    float2 o0 = make_float2(t0.x + t2.x, t0.y + t2.y);
    float2 o2 = make_float2(t0.x - t2.x, t0.y - t2.y);
    float2 o1, o3;
    if (!INV){
        o1 = make_float2(t1.x + t3.y, t1.y - t3.x);
        o3 = make_float2(t1.x - t3.y, t1.y + t3.x);
    } else {
        o1 = make_float2(t1.x - t3.y, t1.y + t3.x);
        o3 = make_float2(t1.x + t3.y, t1.y - t3.x);
    }
    const int base = ((j - jm) << 2) + jm;
    dst[PHI(base)]          = o0;
    dst[PHI(base + Ns)]     = o1;
    dst[PHI(base + 2*Ns)]   = o2;
    dst[PHI(base + 3*Ns)]   = o3;
}

// -------- per-(b,t): packed FFT(ccep,frame) -> G = conj(F)*H -> IFFT -> window --------
__global__ __launch_bounds__(256) void k_filter(const float* __restrict__ ccep,
                                                const float* __restrict__ z,
                                                float* __restrict__ zw){
    __shared__ __align__(16) float2 A[1152];
    __shared__ __align__(16) float2 Bb[1152];
    __shared__ __align__(16) float2 Wt[288];
    const int t = blockIdx.x;
    const int b = blockIdx.y;
    const int tid = threadIdx.x;
    const float PI2 = 6.283185307179586f;

    {
        float s, c;
        __sincosf(-PI2 * (float)tid * (1.0f/1024.0f), &s, &c);
        Wt[PHI(tid)] = make_float2(c, s);
    }
    const float* crow = &ccep[(b*T_LEN + t)*CSTRIDE];
    #pragma unroll
    for (int r = 0; r < 4; ++r){
        int i = tid + (r << 8);
        float av = (i >= 401 && i < 623) ? crow[i - 401] : 0.f;
        float fv = 0.f;
        if (i < 512){
            int zi = t*HOPSZ + i - 255;
            fv = (zi >= 0 && zi < ZLEN) ? z[b*ZLEN + zi] : 0.f;
        }
        A[PHI(i)] = make_float2(av, fv);
    }
    __syncthreads();

    r4stage<1,  false>(A,  Bb, Wt, tid); __syncthreads();
    r4stage<4,  false>(Bb, A,  Wt, tid); __syncthreads();
    r4stage<16, false>(A,  Bb, Wt, tid); __syncthreads();
    r4stage<64, false>(Bb, A,  Wt, tid); __syncthreads();
    r4stage<256,false>(A,  Bb, Wt, tid); __syncthreads();

    const float LOG2_10_DIV10 = 0.33219280948873623f;
    #pragma unroll
    for (int r = 0; r < 4; ++r){
        int i = tid + (r << 8);
        float2 P = Bb[PHI(i)];
        float2 Q = Bb[PHI((1024 - i) & 1023)];
        float Are = 0.5f * (P.x + Q.x);
        float Aim = 0.5f * (P.y - Q.y);
        float Fx  = 0.5f * (P.y + Q.y);
        float Fy  = 0.5f * (Q.x - P.x);
        float mag = exp2f(Are * LOG2_10_DIV10) * (1.0f/1024.0f);
        float s, c;
        sincosf(Aim, &s, &c);
        float Hx = mag * c, Hy = mag * s;
        A[PHI(i)] = make_float2(Fx*Hx + Fy*Hy, Fx*Hy - Fy*Hx);
    }
    __syncthreads();

    r4stage<1,  true>(A,  Bb, Wt, tid); __syncthreads();
    r4stage<4,  true>(Bb, A,  Wt, tid); __syncthreads();
    r4stage<16, true>(A,  Bb, Wt, tid); __syncthreads();
    r4stage<64, true>(Bb, A,  Wt, tid); __syncthreads();
    r4stage<256,true>(A,  Bb, Wt, tid); __syncthreads();

    float* zrow = &zw[(size_t)(b*T_LEN + t)*512];
    #pragma unroll
    for (int r = 0; r < 2; ++r){
        int n = tid + (r << 8);
        float yv = Bb[PHI(511 - n)].x;
        float wv = 0.5f * (1.0f - __cosf(PI2 * (float)n * (1.0f/512.0f)));
        zrow[n] = yv * wv;
    }
}

// -------- OLA + clip --------
__global__ __launch_bounds__(256) void k_ola(const float* __restrict__ zw,
                                             float* __restrict__ out){
    const int t = blockIdx.x;
    const int b = blockIdx.y;
    const int h = threadIdx.x;
    const int tm = (t + T_LEN - 1) % T_LEN;
    float v = zw[(size_t)(b*T_LEN + t)*512 + h]
            + zw[(size_t)(b*T_LEN + tm)*512 + 256 + h];
    v = fminf(fmaxf(v, -1.0f), 1.0f);
    out[(size_t)b*ZLEN + t*HOPSZ + h] = v;
}

extern "C" void kernel_launch(void* const* d_in, const int* in_sizes, int n_in,
                              void* d_out, int out_size, void* d_ws, size_t ws_size,
                              hipStream_t stream){
    const float* x  = (const float*)d_in[0];
    const float* z  = (const float*)d_in[1];
    const float* W1 = (const float*)d_in[2];
    const float* b1 = (const float*)d_in[3];
    const float* W2 = (const float*)d_in[4];
    const float* b2 = (const float*)d_in[5];
    const float* W3 = (const float*)d_in[6];
    const float* b3 = (const float*)d_in[7];
    const float* W4 = (const float*)d_in[8];
    const float* b4 = (const float*)d_in[9];
    float* out = (float*)d_out;
    float* ws  = (float*)d_ws;

    float* h1   = ws;                 // 3,276,800 floats
    float* h2   = ws + 3276800;       // 3,276,800 floats (ccep overlays, 12800*256)
    float* ccep = h2;
    float* zwb  = ws + 6553600;       // 6,553,600 floats
    // transposed float4 weights in the FRONT of zwb (read only by convs,
    // overwritten later by k_filter — stream-ordered, safe)
    float4* w1t = (float4*)(zwb);               // 20480 float4
    float4* w2t = (float4*)(zwb + 81920);       //  8192 float4
    float4* w3t = (float4*)(zwb + 114688);      //  8192 float4
    float4* w4t = (float4*)(zwb + 147456);      // 65536 float4 (ends @409600 floats)

    dim3 blk(256);
    dim3 gwt(256, 4);
    dim3 gconv(T_LEN/16, B_SZ);       // (50,16)
    dim3 gf(T_LEN, B_SZ);             // (800,16)

    k_wtrans<<<gwt, blk, 0, stream>>>(W1, W2, W3, W4, w1t, w2t, w3t, w4t);
    k_conv1<<<gconv, blk, 0, stream>>>(x, w1t, b1, h1);
    k_convg<<<gconv, blk, 0, stream>>>(h1, w2t, b2, h2);
    k_convg<<<gconv, blk, 0, stream>>>(h2, w3t, b3, h1);
    k_conv4<<<gconv, dim3(512), 0, stream>>>(h1, w4t, b4, ccep);
    k_filter<<<gf, blk, 0, stream>>>(ccep, z, zwb);
    k_ola<<<gf, blk, 0, stream>>>(zwb, out);
}

// Round 10
// 180.914 us; speedup vs baseline: 1.4006x; 1.3947x over previous
//
#include <hip/hip_runtime.h>
#include <hip/hip_bf16.h>

#define T_LEN 800
#define B_SZ  16
#define D_IN  80
#define CCH   256
#define OUT_CH 222
#define HOPSZ 256
#define WINSZ 512
#define ZLEN  (T_LEN*HOPSZ)   // 204800
#define CSTRIDE 256           // ccep row stride ([t][co] layout)

#define PHI(i) ((i) + ((i)>>3))

typedef short short8 __attribute__((ext_vector_type(8)));
typedef float f32x4 __attribute__((ext_vector_type(4)));

__device__ __forceinline__ float2 cmul(float2 a, float2 b){
    return make_float2(a.x*b.x - a.y*b.y, a.x*b.y + a.y*b.x);
}

// -------- weight transpose: float4 [ci][co] for conv1-3; split-bf16 fragment layout for conv4 --------
__global__ __launch_bounds__(256) void k_wtrans(const float* __restrict__ W1,
                                                const float* __restrict__ W2,
                                                const float* __restrict__ W3,
                                                const float* __restrict__ W4,
                                                float4* __restrict__ w1t,
                                                float4* __restrict__ w2t,
                                                float4* __restrict__ w3t,
                                                __hip_bfloat16* __restrict__ wfhi,
                                                __hip_bfloat16* __restrict__ wflo){
    const int i = blockIdx.x*256 + threadIdx.x;
    switch (blockIdx.y){
    case 0: if (i < 80*256){
        int ci = i >> 8, co = i & 255;
        const float* s = &W1[(co*80 + ci)*3];
        w1t[i] = make_float4(s[0], s[1], s[2], 0.f);
    } break;
    case 1: if (i < 32*256){
        int cil = i >> 8, co = i & 255;
        const float* s = &W2[(co*32 + cil)*3];
        w2t[i] = make_float4(s[0], s[1], s[2], 0.f);
    } break;
    case 2: if (i < 32*256){
        int cil = i >> 8, co = i & 255;
        const float* s = &W3[(co*32 + cil)*3];
        w3t[i] = make_float4(s[0], s[1], s[2], 0.f);
    } break;
    default: if (i < 768*256){
        // k = d*256 + ci ; fragment-linear: chunk = (kt*4+g)*256+co holds k=kt*32+g*8+e
        int k = i >> 8, co = i & 255;
        int d = k >> 8, ci = k & 255;
        float w = 0.f;
        if (co < OUT_CH){
            float q = (co < 111) ? (float)(111 - co) : (float)(co - 110);
            w = W4[(co*256 + ci)*3 + d] / q;   // fold 1/quef into weights
        }
        __hip_bfloat16 h = __float2bfloat16(w);
        __hip_bfloat16 l = __float2bfloat16(w - __bfloat162float(h));
        int kt = k >> 5, g = (k >> 3) & 3, e = k & 7;
        int idx = ((kt*4 + g)*256 + co)*8 + e;
        wfhi[idx] = h;
        wflo[idx] = l;
    } break;
    }
}

// -------- conv1: x (B,T,80) -> h1 (B,T,256) [t][c], relu --------
__global__ __launch_bounds__(256) void k_conv1(const float* __restrict__ x,
                                               const float4* __restrict__ Wt,
                                               const float* __restrict__ bias,
                                               float* __restrict__ out){
    __shared__ __align__(16) float xs[80*20];
    const int t0 = blockIdx.x * 16;
    const int b  = blockIdx.y;
    const int tid = threadIdx.x;
    const int co = tid;
    for (int i = tid; i < 80*18; i += 256){
        int tt = i / 80, ci = i - tt*80;
        int t = t0 - 1 + tt;
        xs[ci*20 + tt] = (t >= 0 && t < T_LEN) ? x[(b*T_LEN + t)*D_IN + ci] : 0.f;
    }
    __syncthreads();
    float acc[16];
    float bv = bias[co];
    #pragma unroll
    for (int t = 0; t < 16; ++t) acc[t] = bv;
    const float4* wp = Wt + co;
    float4 w = *wp;
    for (int ci = 0; ci < 80; ++ci){
        wp += 256;
        float4 wn = *wp;   // prefetch; overrun lands in adjacent weight buffer, unused
        const float* xp = &xs[ci*20];
        float4 v0 = *(const float4*)(xp);
        float4 v1 = *(const float4*)(xp + 4);
        float4 v2 = *(const float4*)(xp + 8);
        float4 v3 = *(const float4*)(xp + 12);
        float2 v4 = *(const float2*)(xp + 16);
        float xr[18] = {v0.x,v0.y,v0.z,v0.w, v1.x,v1.y,v1.z,v1.w,
                        v2.x,v2.y,v2.z,v2.w, v3.x,v3.y,v3.z,v3.w, v4.x,v4.y};
        #pragma unroll
        for (int t = 0; t < 16; ++t){
            acc[t] = fmaf(xr[t],   w.x, acc[t]);
            acc[t] = fmaf(xr[t+1], w.y, acc[t]);
            acc[t] = fmaf(xr[t+2], w.z, acc[t]);
        }
        w = wn;
    }
    #pragma unroll
    for (int t = 0; t < 16; ++t)
        out[(b*T_LEN + t0 + t)*CCH + co] = fmaxf(acc[t], 0.f);
}

// -------- grouped conv (256->256, groups=8), relu, f32 out (conv2) --------
__global__ __launch_bounds__(256) void k_convg(const float* __restrict__ in,
                                               const float4* __restrict__ Wt,
                                               const float* __restrict__ bias,
                                               float* __restrict__ out){
    __shared__ __align__(16) float hs[256*20];
    const int t0 = blockIdx.x * 16;
    const int b  = blockIdx.y;
    const int tid = threadIdx.x;
    const int co = tid;
    const int gbase = (co >> 5) << 5;
    for (int i = tid; i < 256*18; i += 256){
        int tt = i >> 8, ci = i & 255;
        int t = t0 - 1 + tt;
        hs[ci*20 + tt] = (t >= 0 && t < T_LEN) ? in[(b*T_LEN + t)*CCH + ci] : 0.f;
    }
    __syncthreads();
    float acc[16];
    float bv = bias[co];
    #pragma unroll
    for (int t = 0; t < 16; ++t) acc[t] = bv;
    const float4* wp = Wt + co;
    float4 w = *wp;
    for (int cil = 0; cil < 32; ++cil){
        wp += 256;
        float4 wn = *wp;
        const float* xp = &hs[(gbase + cil)*20];
        float4 v0 = *(const float4*)(xp);
        float4 v1 = *(const float4*)(xp + 4);
        float4 v2 = *(const float4*)(xp + 8);
        float4 v3 = *(const float4*)(xp + 12);
        float2 v4 = *(const float2*)(xp + 16);
        float xr[18] = {v0.x,v0.y,v0.z,v0.w, v1.x,v1.y,v1.z,v1.w,
                        v2.x,v2.y,v2.z,v2.w, v3.x,v3.y,v3.z,v3.w, v4.x,v4.y};
        #pragma unroll
        for (int t = 0; t < 16; ++t){
            acc[t] = fmaf(xr[t],   w.x, acc[t]);
            acc[t] = fmaf(xr[t+1], w.y, acc[t]);
            acc[t] = fmaf(xr[t+2], w.z, acc[t]);
        }
        w = wn;
    }
    #pragma unroll
    for (int t = 0; t < 16; ++t)
        out[(b*T_LEN + t0 + t)*CCH + co] = fmaxf(acc[t], 0.f);
}

// -------- conv3: same as convg but emits split-bf16 planes (for MFMA conv4) --------
__global__ __launch_bounds__(256) void k_convg_bf16(const float* __restrict__ in,
                                                    const float4* __restrict__ Wt,
                                                    const float* __restrict__ bias,
                                                    __hip_bfloat16* __restrict__ ohi,
                                                    __hip_bfloat16* __restrict__ olo){
    __shared__ __align__(16) float hs[256*20];
    const int t0 = blockIdx.x * 16;
    const int b  = blockIdx.y;
    const int tid = threadIdx.x;
    const int co = tid;
    const int gbase = (co >> 5) << 5;
    for (int i = tid; i < 256*18; i += 256){
        int tt = i >> 8, ci = i & 255;
        int t = t0 - 1 + tt;
        hs[ci*20 + tt] = (t >= 0 && t < T_LEN) ? in[(b*T_LEN + t)*CCH + ci] : 0.f;
    }
    __syncthreads();
    float acc[16];
    float bv = bias[co];
    #pragma unroll
    for (int t = 0; t < 16; ++t) acc[t] = bv;
    const float4* wp = Wt + co;
    float4 w = *wp;
    for (int cil = 0; cil < 32; ++cil){
        wp += 256;
        float4 wn = *wp;
        const float* xp = &hs[(gbase + cil)*20];
        float4 v0 = *(const float4*)(xp);
        float4 v1 = *(const float4*)(xp + 4);
        float4 v2 = *(const float4*)(xp + 8);
        float4 v3 = *(const float4*)(xp + 12);
        float2 v4 = *(const float2*)(xp + 16);
        float xr[18] = {v0.x,v0.y,v0.z,v0.w, v1.x,v1.y,v1.z,v1.w,
                        v2.x,v2.y,v2.z,v2.w, v3.x,v3.y,v3.z,v3.w, v4.x,v4.y};
        #pragma unroll
        for (int t = 0; t < 16; ++t){
            acc[t] = fmaf(xr[t],   w.x, acc[t]);
            acc[t] = fmaf(xr[t+1], w.y, acc[t]);
            acc[t] = fmaf(xr[t+2], w.z, acc[t]);
        }
        w = wn;
    }
    #pragma unroll
    for (int t = 0; t < 16; ++t){
        float v = fmaxf(acc[t], 0.f);
        __hip_bfloat16 h = __float2bfloat16(v);
        __hip_bfloat16 l = __float2bfloat16(v - __bfloat162float(h));
        size_t idx = (size_t)(b*T_LEN + t0 + t)*CCH + co;
        ohi[idx] = h;
        olo[idx] = l;
    }
}

// -------- conv4 via MFMA 16x16x32 bf16, split hi/lo (3 passes fused in K loop) --------
// block: 256 thr = 4 waves; tile 32t x 128co; wave = 32t x 32co; grid (400, 2)
__global__ __launch_bounds__(256) void k_conv4(const __hip_bfloat16* __restrict__ hhi,
                                               const __hip_bfloat16* __restrict__ hlo,
                                               const __hip_bfloat16* __restrict__ wfhi,
                                               const __hip_bfloat16* __restrict__ wflo,
                                               const float* __restrict__ bias,
                                               float* __restrict__ ccep){
    __shared__ __align__(16) unsigned char aLds[2][34*512];   // [plane][row 34][ci 256 bf16], XOR-swizzled
    const int gx = blockIdx.x;              // 400 = 16 b * 25 t-tiles
    const int b  = gx / 25;
    const int t0 = (gx - b*25) * 32;
    const int coBase = blockIdx.y << 7;     // 0 or 128
    const int tid = threadIdx.x;
    const int wave = tid >> 6;
    const int l = tid & 63;
    const int l15 = l & 15, lg = l >> 4;

    // stage 34 rows x 256 ci x {hi,lo}: global 16B chunks -> swizzled LDS
    for (int i = tid; i < 2*1088; i += 256){
        int p = (i >= 1088);
        int c = i - (p ? 1088 : 0);
        int r = c >> 5, c16 = c & 31;
        int t = t0 - 1 + r;
        uint4 v = make_uint4(0u,0u,0u,0u);
        if (t >= 0 && t < T_LEN){
            const __hip_bfloat16* src = (p ? hlo : hhi) + (((size_t)(b*T_LEN + t)) << 8) + (c16 << 3);
            v = *(const uint4*)src;
        }
        int off = (r << 9) + (c16 << 4);
        off ^= (r & 7) << 4;
        *(uint4*)(&aLds[p][off]) = v;
    }
    __syncthreads();

    const int co0 = coBase + (wave << 5);   // wave's 32-co strip
    f32x4 acc[2][2];                        // [msub][nsub]
    #pragma unroll
    for (int n = 0; n < 2; ++n){
        int co = co0 + (n << 4) + l15;
        float bq = 0.f;
        if (co < OUT_CH){
            float q = (co < 111) ? (float)(111 - co) : (float)(co - 110);
            bq = bias[co] / q;
        }
        acc[0][n] = f32x4{bq, bq, bq, bq};
        acc[1][n] = f32x4{bq, bq, bq, bq};
    }

    for (int kt = 0; kt < 24; ++kt){
        const int d   = kt >> 3;
        const int cib = (kt & 7) << 6;      // ci0*2 bytes
        short8 ah[2], al[2];
        #pragma unroll
        for (int m = 0; m < 2; ++m){
            int r = l15 + d + (m << 4);
            int off = (r << 9) + cib + (lg << 4);
            off ^= (r & 7) << 4;
            ah[m] = __builtin_bit_cast(short8, *(const uint4*)(&aLds[0][off]));
            al[m] = __builtin_bit_cast(short8, *(const uint4*)(&aLds[1][off]));
        }
        #pragma unroll
        for (int n = 0; n < 2; ++n){
            int co = co0 + (n << 4) + l15;
            size_t woff = ((size_t)((kt << 2) + lg) << 8) + co;   // 16B chunk index
            short8 bh = __builtin_bit_cast(short8, *(const uint4*)(wfhi + (woff << 3)));
            short8 bl = __builtin_bit_cast(short8, *(const uint4*)(wflo + (woff << 3)));
            #pragma unroll
            for (int m = 0; m < 2; ++m){
                acc[m][n] = __builtin_amdgcn_mfma_f32_16x16x32_bf16(ah[m], bh, acc[m][n], 0, 0, 0);
                acc[m][n] = __builtin_amdgcn_mfma_f32_16x16x32_bf16(ah[m], bl, acc[m][n], 0, 0, 0);
                acc[m][n] = __builtin_amdgcn_mfma_f32_16x16x32_bf16(al[m], bh, acc[m][n], 0, 0, 0);
            }
        }
    }

    // epilogue: D row = (lane>>4)*4 + j (t), col = lane&15 (co)  [m89/m91]
    #pragma unroll
    for (int m = 0; m < 2; ++m){
        #pragma unroll
        for (int n = 0; n < 2; ++n){
            int co = co0 + (n << 4) + l15;
            #pragma unroll
            for (int j = 0; j < 4; ++j){
                int t = t0 + (m << 4) + (lg << 2) + j;
                ccep[((size_t)(b*T_LEN + t) << 8) + co] = acc[m][n][j];
            }
        }
    }
}

// -------- radix-4 Stockham stage --------
template<int Ns, bool INV>
__device__ __forceinline__ void r4stage(const float2* __restrict__ src,
                                        float2* __restrict__ dst,
                                        const float2* __restrict__ Wt,
                                        int j){
    const int jm = j & (Ns - 1);
    float2 v0 = src[PHI(j)];
    float2 v1 = src[PHI(j + 256)];
    float2 v2 = src[PHI(j + 512)];
    float2 v3 = src[PHI(j + 768)];
    if (Ns > 1){
        float2 w1 = Wt[PHI(jm * (256 / Ns))];
        if (INV) w1.y = -w1.y;
        float2 w2 = cmul(w1, w1);
        float2 w3 = cmul(w2, w1);
        v1 = cmul(v1, w1);
        v2 = cmul(v2, w2);
        v3 = cmul(v3, w3);
    }
    float2 t0 = make_float2(v0.x + v2.x, v0.y + v2.y);
    float2 t1 = make_float2(v0.x - v2.x, v0.y - v2.y);
    float2 t2 = make_float2(v1.x + v3.x, v1.y + v3.y);
    float2 t3 = make_float2(v1.x - v3.x, v1.y - v3.y);
    float2 o0 = make_float2(t0.x + t2.x, t0.y + t2.y);
    float2 o2 = make_float2(t0.x - t2.x, t0.y - t2.y);
    float2 o1, o3;
    if (!INV){
        o1 = make_float2(t1.x + t3.y, t1.y - t3.x);
        o3 = make_float2(t1.x - t3.y, t1.y + t3.x);
    } else {
        o1 = make_float2(t1.x - t3.y, t1.y + t3.x);
        o3 = make_float2(t1.x + t3.y, t1.y - t3.x);
    }
    const int base = ((j - jm) << 2) + jm;
    dst[PHI(base)]          = o0;
    dst[PHI(base + Ns)]     = o1;
    dst[PHI(base + 2*Ns)]   = o2;
    dst[PHI(base + 3*Ns)]   = o3;
}

// -------- per-(b,t): packed FFT(ccep,frame) -> G = conj(F)*H -> IFFT -> window --------
__global__ __launch_bounds__(256) void k_filter(const float* __restrict__ ccep,
                                                const float* __restrict__ z,
                                                float* __restrict__ zw){
    __shared__ __align__(16) float2 A[1152];
    __shared__ __align__(16) float2 Bb[1152];
    __shared__ __align__(16) float2 Wt[288];
    const int t = blockIdx.x;
    const int b = blockIdx.y;
    const int tid = threadIdx.x;
    const float PI2 = 6.283185307179586f;

    {
        float s, c;
        __sincosf(-PI2 * (float)tid * (1.0f/1024.0f), &s, &c);
        Wt[PHI(tid)] = make_float2(c, s);
    }
    const float* crow = &ccep[(b*T_LEN + t)*CSTRIDE];
    #pragma unroll
    for (int r = 0; r < 4; ++r){
        int i = tid + (r << 8);
        float av = (i >= 401 && i < 623) ? crow[i - 401] : 0.f;
        float fv = 0.f;
        if (i < 512){
            int zi = t*HOPSZ + i - 255;
            fv = (zi >= 0 && zi < ZLEN) ? z[b*ZLEN + zi] : 0.f;
        }
        A[PHI(i)] = make_float2(av, fv);
    }
    __syncthreads();

    r4stage<1,  false>(A,  Bb, Wt, tid); __syncthreads();
    r4stage<4,  false>(Bb, A,  Wt, tid); __syncthreads();
    r4stage<16, false>(A,  Bb, Wt, tid); __syncthreads();
    r4stage<64, false>(Bb, A,  Wt, tid); __syncthreads();
    r4stage<256,false>(A,  Bb, Wt, tid); __syncthreads();

    const float LOG2_10_DIV10 = 0.33219280948873623f;
    #pragma unroll
    for (int r = 0; r < 4; ++r){
        int i = tid + (r << 8);
        float2 P = Bb[PHI(i)];
        float2 Q = Bb[PHI((1024 - i) & 1023)];
        float Are = 0.5f * (P.x + Q.x);
        float Aim = 0.5f * (P.y - Q.y);
        float Fx  = 0.5f * (P.y + Q.y);
        float Fy  = 0.5f * (Q.x - P.x);
        float mag = exp2f(Are * LOG2_10_DIV10) * (1.0f/1024.0f);
        float s, c;
        sincosf(Aim, &s, &c);
        float Hx = mag * c, Hy = mag * s;
        A[PHI(i)] = make_float2(Fx*Hx + Fy*Hy, Fx*Hy - Fy*Hx);
    }
    __syncthreads();

    r4stage<1,  true>(A,  Bb, Wt, tid); __syncthreads();
    r4stage<4,  true>(Bb, A,  Wt, tid); __syncthreads();
    r4stage<16, true>(A,  Bb, Wt, tid); __syncthreads();
    r4stage<64, true>(Bb, A,  Wt, tid); __syncthreads();
    r4stage<256,true>(A,  Bb, Wt, tid); __syncthreads();

    float* zrow = &zw[(size_t)(b*T_LEN + t)*512];
    #pragma unroll
    for (int r = 0; r < 2; ++r){
        int n = tid + (r << 8);
        float yv = Bb[PHI(511 - n)].x;
        float wv = 0.5f * (1.0f - __cosf(PI2 * (float)n * (1.0f/512.0f)));
        zrow[n] = yv * wv;
    }
}

// -------- OLA + clip --------
__global__ __launch_bounds__(256) void k_ola(const float* __restrict__ zw,
                                             float* __restrict__ out){
    const int t = blockIdx.x;
    const int b = blockIdx.y;
    const int h = threadIdx.x;
    const int tm = (t + T_LEN - 1) % T_LEN;
    float v = zw[(size_t)(b*T_LEN + t)*512 + h]
            + zw[(size_t)(b*T_LEN + tm)*512 + 256 + h];
    v = fminf(fmaxf(v, -1.0f), 1.0f);
    out[(size_t)b*ZLEN + t*HOPSZ + h] = v;
}

extern "C" void kernel_launch(void* const* d_in, const int* in_sizes, int n_in,
                              void* d_out, int out_size, void* d_ws, size_t ws_size,
                              hipStream_t stream){
    const float* x  = (const float*)d_in[0];
    const float* z  = (const float*)d_in[1];
    const float* W1 = (const float*)d_in[2];
    const float* b1 = (const float*)d_in[3];
    const float* W2 = (const float*)d_in[4];
    const float* b2 = (const float*)d_in[5];
    const float* W3 = (const float*)d_in[6];
    const float* b3 = (const float*)d_in[7];
    const float* W4 = (const float*)d_in[8];
    const float* b4 = (const float*)d_in[9];
    float* out = (float*)d_out;
    float* ws  = (float*)d_ws;

    float* h1   = ws;                 // 3,276,800 floats (becomes h3 bf16 planes after conv3)
    float* h2   = ws + 3276800;       // 3,276,800 floats (ccep overlays, 12800*256)
    float* ccep = h2;
    float* zwb  = ws + 6553600;       // 6,553,600 floats
    // conv3 output planes overlay h1 (h1 dead after conv2): exactly 13,107,200 B
    __hip_bfloat16* h3hi = (__hip_bfloat16*)h1;
    __hip_bfloat16* h3lo = h3hi + 3276800;
    // weights in FRONT of zwb (read only by convs, overwritten later by k_filter)
    float4* w1t = (float4*)(zwb);                         // 20480 f4  (81920 fl)
    float4* w2t = (float4*)(zwb + 81920);                 //  8192 f4  (32768 fl)
    float4* w3t = (float4*)(zwb + 114688);                //  8192 f4
    __hip_bfloat16* wfhi = (__hip_bfloat16*)(zwb + 147456);  // 196608 bf16
    __hip_bfloat16* wflo = wfhi + 196608;                    // ends @ zwb+344064 fl

    dim3 blk(256);
    dim3 gwt(768, 4);
    dim3 gconv(T_LEN/16, B_SZ);       // (50,16)
    dim3 gc4(400, 2);                 // 32t-tiles x 2 co-halves
    dim3 gf(T_LEN, B_SZ);             // (800,16)

    k_wtrans<<<gwt, blk, 0, stream>>>(W1, W2, W3, W4, w1t, w2t, w3t, wfhi, wflo);
    k_conv1<<<gconv, blk, 0, stream>>>(x, w1t, b1, h1);
    k_convg<<<gconv, blk, 0, stream>>>(h1, w2t, b2, h2);
    k_convg_bf16<<<gconv, blk, 0, stream>>>(h2, w3t, b3, h3hi, h3lo);
    k_conv4<<<gc4, blk, 0, stream>>>(h3hi, h3lo, wfhi, wflo, b4, ccep);
    k_filter<<<gf, blk, 0, stream>>>(ccep, z, zwb);
    k_ola<<<gf, blk, 0, stream>>>(zwb, out);
}

// Round 12
// 175.790 us; speedup vs baseline: 1.4414x; 1.0291x over previous
//
#include <hip/hip_runtime.h>
#include <hip/hip_bf16.h>

#define T_LEN 800
#define B_SZ  16
#define D_IN  80
#define CCH   256
#define OUT_CH 222
#define HOPSZ 256
#define WINSZ 512
#define ZLEN  (T_LEN*HOPSZ)   // 204800
#define CSTRIDE 256           // ccep row stride ([t][co] layout)

#define PHI(i) ((i) + ((i)>>3))

typedef short short8 __attribute__((ext_vector_type(8)));
typedef float f32x4 __attribute__((ext_vector_type(4)));

__device__ __forceinline__ float2 cmul(float2 a, float2 b){
    return make_float2(a.x*b.x - a.y*b.y, a.x*b.y + a.y*b.x);
}

// -------- weight transpose: float4 [ci][co] for conv1-3; split-bf16 fragment layout for conv4 --------
__global__ __launch_bounds__(256) void k_wtrans(const float* __restrict__ W1,
                                                const float* __restrict__ W2,
                                                const float* __restrict__ W3,
                                                const float* __restrict__ W4,
                                                float4* __restrict__ w1t,
                                                float4* __restrict__ w2t,
                                                float4* __restrict__ w3t,
                                                __hip_bfloat16* __restrict__ wfhi,
                                                __hip_bfloat16* __restrict__ wflo){
    const int i = blockIdx.x*256 + threadIdx.x;
    switch (blockIdx.y){
    case 0: if (i < 80*256){
        int ci = i >> 8, co = i & 255;
        const float* s = &W1[(co*80 + ci)*3];
        w1t[i] = make_float4(s[0], s[1], s[2], 0.f);
    } break;
    case 1: if (i < 32*256){
        int cil = i >> 8, co = i & 255;
        const float* s = &W2[(co*32 + cil)*3];
        w2t[i] = make_float4(s[0], s[1], s[2], 0.f);
    } break;
    case 2: if (i < 32*256){
        int cil = i >> 8, co = i & 255;
        const float* s = &W3[(co*32 + cil)*3];
        w3t[i] = make_float4(s[0], s[1], s[2], 0.f);
    } break;
    default: if (i < 768*256){
        int k = i >> 8, co = i & 255;
        int d = k >> 8, ci = k & 255;
        float w = 0.f;
        if (co < OUT_CH){
            float q = (co < 111) ? (float)(111 - co) : (float)(co - 110);
            w = W4[(co*256 + ci)*3 + d] / q;   // fold 1/quef into weights
        }
        __hip_bfloat16 h = __float2bfloat16(w);
        __hip_bfloat16 l = __float2bfloat16(w - __bfloat162float(h));
        int kt = k >> 5, g = (k >> 3) & 3, e = k & 7;
        int idx = ((kt*4 + g)*256 + co)*8 + e;
        wfhi[idx] = h;
        wflo[idx] = l;
    } break;
    }
}

// -------- conv1: x (B,T,80) -> h1 (B,T,256) [t][c], relu --------
__global__ __launch_bounds__(256) void k_conv1(const float* __restrict__ x,
                                               const float4* __restrict__ Wt,
                                               const float* __restrict__ bias,
                                               float* __restrict__ out){
    __shared__ __align__(16) float xs[80*20];
    const int t0 = blockIdx.x * 16;
    const int b  = blockIdx.y;
    const int tid = threadIdx.x;
    const int co = tid;
    for (int i = tid; i < 80*18; i += 256){
        int tt = i / 80, ci = i - tt*80;
        int t = t0 - 1 + tt;
        xs[ci*20 + tt] = (t >= 0 && t < T_LEN) ? x[(b*T_LEN + t)*D_IN + ci] : 0.f;
    }
    __syncthreads();
    float acc[16];
    float bv = bias[co];
    #pragma unroll
    for (int t = 0; t < 16; ++t) acc[t] = bv;
    const float4* wp = Wt + co;
    float4 w = *wp;
    for (int ci = 0; ci < 80; ++ci){
        wp += 256;
        float4 wn = *wp;   // prefetch; overrun lands in adjacent weight buffer, unused
        const float* xp = &xs[ci*20];
        float4 v0 = *(const float4*)(xp);
        float4 v1 = *(const float4*)(xp + 4);
        float4 v2 = *(const float4*)(xp + 8);
        float4 v3 = *(const float4*)(xp + 12);
        float2 v4 = *(const float2*)(xp + 16);
        float xr[18] = {v0.x,v0.y,v0.z,v0.w, v1.x,v1.y,v1.z,v1.w,
                        v2.x,v2.y,v2.z,v2.w, v3.x,v3.y,v3.z,v3.w, v4.x,v4.y};
        #pragma unroll
        for (int t = 0; t < 16; ++t){
            acc[t] = fmaf(xr[t],   w.x, acc[t]);
            acc[t] = fmaf(xr[t+1], w.y, acc[t]);
            acc[t] = fmaf(xr[t+2], w.z, acc[t]);
        }
        w = wn;
    }
    #pragma unroll
    for (int t = 0; t < 16; ++t)
        out[(b*T_LEN + t0 + t)*CCH + co] = fmaxf(acc[t], 0.f);
}

// -------- grouped conv (256->256, groups=8), relu, f32 out (conv2) --------
__global__ __launch_bounds__(256) void k_convg(const float* __restrict__ in,
                                               const float4* __restrict__ Wt,
                                               const float* __restrict__ bias,
                                               float* __restrict__ out){
    __shared__ __align__(16) float hs[256*20];
    const int t0 = blockIdx.x * 16;
    const int b  = blockIdx.y;
    const int tid = threadIdx.x;
    const int co = tid;
    const int gbase = (co >> 5) << 5;
    for (int i = tid; i < 256*18; i += 256){
        int tt = i >> 8, ci = i & 255;
        int t = t0 - 1 + tt;
        hs[ci*20 + tt] = (t >= 0 && t < T_LEN) ? in[(b*T_LEN + t)*CCH + ci] : 0.f;
    }
    __syncthreads();
    float acc[16];
    float bv = bias[co];
    #pragma unroll
    for (int t = 0; t < 16; ++t) acc[t] = bv;
    const float4* wp = Wt + co;
    float4 w = *wp;
    for (int cil = 0; cil < 32; ++cil){
        wp += 256;
        float4 wn = *wp;
        const float* xp = &hs[(gbase + cil)*20];
        float4 v0 = *(const float4*)(xp);
        float4 v1 = *(const float4*)(xp + 4);
        float4 v2 = *(const float4*)(xp + 8);
        float4 v3 = *(const float4*)(xp + 12);
        float2 v4 = *(const float2*)(xp + 16);
        float xr[18] = {v0.x,v0.y,v0.z,v0.w, v1.x,v1.y,v1.z,v1.w,
                        v2.x,v2.y,v2.z,v2.w, v3.x,v3.y,v3.z,v3.w, v4.x,v4.y};
        #pragma unroll
        for (int t = 0; t < 16; ++t){
            acc[t] = fmaf(xr[t],   w.x, acc[t]);
            acc[t] = fmaf(xr[t+1], w.y, acc[t]);
            acc[t] = fmaf(xr[t+2], w.z, acc[t]);
        }
        w = wn;
    }
    #pragma unroll
    for (int t = 0; t < 16; ++t)
        out[(b*T_LEN + t0 + t)*CCH + co] = fmaxf(acc[t], 0.f);
}

// -------- conv3: same as convg but emits split-bf16 planes (for MFMA conv4) --------
__global__ __launch_bounds__(256) void k_convg_bf16(const float* __restrict__ in,
                                                    const float4* __restrict__ Wt,
                                                    const float* __restrict__ bias,
                                                    __hip_bfloat16* __restrict__ ohi,
                                                    __hip_bfloat16* __restrict__ olo){
    __shared__ __align__(16) float hs[256*20];
    const int t0 = blockIdx.x * 16;
    const int b  = blockIdx.y;
    const int tid = threadIdx.x;
    const int co = tid;
    const int gbase = (co >> 5) << 5;
    for (int i = tid; i < 256*18; i += 256){
        int tt = i >> 8, ci = i & 255;
        int t = t0 - 1 + tt;
        hs[ci*20 + tt] = (t >= 0 && t < T_LEN) ? in[(b*T_LEN + t)*CCH + ci] : 0.f;
    }
    __syncthreads();
    float acc[16];
    float bv = bias[co];
    #pragma unroll
    for (int t = 0; t < 16; ++t) acc[t] = bv;
    const float4* wp = Wt + co;
    float4 w = *wp;
    for (int cil = 0; cil < 32; ++cil){
        wp += 256;
        float4 wn = *wp;
        const float* xp = &hs[(gbase + cil)*20];
        float4 v0 = *(const float4*)(xp);
        float4 v1 = *(const float4*)(xp + 4);
        float4 v2 = *(const float4*)(xp + 8);
        float4 v3 = *(const float4*)(xp + 12);
        float2 v4 = *(const float2*)(xp + 16);
        float xr[18] = {v0.x,v0.y,v0.z,v0.w, v1.x,v1.y,v1.z,v1.w,
                        v2.x,v2.y,v2.z,v2.w, v3.x,v3.y,v3.z,v3.w, v4.x,v4.y};
        #pragma unroll
        for (int t = 0; t < 16; ++t){
            acc[t] = fmaf(xr[t],   w.x, acc[t]);
            acc[t] = fmaf(xr[t+1], w.y, acc[t]);
            acc[t] = fmaf(xr[t+2], w.z, acc[t]);
        }
        w = wn;
    }
    #pragma unroll
    for (int t = 0; t < 16; ++t){
        float v = fmaxf(acc[t], 0.f);
        __hip_bfloat16 h = __float2bfloat16(v);
        __hip_bfloat16 l = __float2bfloat16(v - __bfloat162float(h));
        size_t idx = (size_t)(b*T_LEN + t0 + t)*CCH + co;
        ohi[idx] = h;
        olo[idx] = l;
    }
}

// -------- conv4 via MFMA 16x16x32 bf16, split hi/lo (3 passes fused in K loop) --------
__global__ __launch_bounds__(256) void k_conv4(const __hip_bfloat16* __restrict__ hhi,
                                               const __hip_bfloat16* __restrict__ hlo,
                                               const __hip_bfloat16* __restrict__ wfhi,
                                               const __hip_bfloat16* __restrict__ wflo,
                                               const float* __restrict__ bias,
                                               float* __restrict__ ccep){
    __shared__ __align__(16) unsigned char aLds[2][34*512];
    const int gx = blockIdx.x;              // 400 = 16 b * 25 t-tiles
    const int b  = gx / 25;
    const int t0 = (gx - b*25) * 32;
    const int coBase = blockIdx.y << 7;     // 0 or 128
    const int tid = threadIdx.x;
    const int wave = tid >> 6;
    const int l = tid & 63;
    const int l15 = l & 15, lg = l >> 4;

    for (int i = tid; i < 2*1088; i += 256){
        int p = (i >= 1088);
        int c = i - (p ? 1088 : 0);
        int r = c >> 5, c16 = c & 31;
        int t = t0 - 1 + r;
        uint4 v = make_uint4(0u,0u,0u,0u);
        if (t >= 0 && t < T_LEN){
            const __hip_bfloat16* src = (p ? hlo : hhi) + (((size_t)(b*T_LEN + t)) << 8) + (c16 << 3);
            v = *(const uint4*)src;
        }
        int off = (r << 9) + (c16 << 4);
        off ^= (r & 7) << 4;
        *(uint4*)(&aLds[p][off]) = v;
    }
    __syncthreads();

    const int co0 = coBase + (wave << 5);
    f32x4 acc[2][2];
    #pragma unroll
    for (int n = 0; n < 2; ++n){
        int co = co0 + (n << 4) + l15;
        float bq = 0.f;
        if (co < OUT_CH){
            float q = (co < 111) ? (float)(111 - co) : (float)(co - 110);
            bq = bias[co] / q;
        }
        acc[0][n] = f32x4{bq, bq, bq, bq};
        acc[1][n] = f32x4{bq, bq, bq, bq};
    }

    for (int kt = 0; kt < 24; ++kt){
        const int d   = kt >> 3;
        const int cib = (kt & 7) << 6;
        short8 ah[2], al[2];
        #pragma unroll
        for (int m = 0; m < 2; ++m){
            int r = l15 + d + (m << 4);
            int off = (r << 9) + cib + (lg << 4);
            off ^= (r & 7) << 4;
            ah[m] = __builtin_bit_cast(short8, *(const uint4*)(&aLds[0][off]));
            al[m] = __builtin_bit_cast(short8, *(const uint4*)(&aLds[1][off]));
        }
        #pragma unroll
        for (int n = 0; n < 2; ++n){
            int co = co0 + (n << 4) + l15;
            size_t woff = ((size_t)((kt << 2) + lg) << 8) + co;
            short8 bh = __builtin_bit_cast(short8, *(const uint4*)(wfhi + (woff << 3)));
            short8 bl = __builtin_bit_cast(short8, *(const uint4*)(wflo + (woff << 3)));
            #pragma unroll
            for (int m = 0; m < 2; ++m){
                acc[m][n] = __builtin_amdgcn_mfma_f32_16x16x32_bf16(ah[m], bh, acc[m][n], 0, 0, 0);
                acc[m][n] = __builtin_amdgcn_mfma_f32_16x16x32_bf16(ah[m], bl, acc[m][n], 0, 0, 0);
                acc[m][n] = __builtin_amdgcn_mfma_f32_16x16x32_bf16(al[m], bh, acc[m][n], 0, 0, 0);
            }
        }
    }

    #pragma unroll
    for (int m = 0; m < 2; ++m){
        #pragma unroll
        for (int n = 0; n < 2; ++n){
            int co = co0 + (n << 4) + l15;
            #pragma unroll
            for (int j = 0; j < 4; ++j){
                int t = t0 + (m << 4) + (lg << 2) + j;
                ccep[((size_t)(b*T_LEN + t) << 8) + co] = acc[m][n][j];
            }
        }
    }
}

// -------- radix-4 Stockham stage (N4 = N/4 butterflies; twiddles from 768-entry table) --------
template<int N4, int Ns, bool INV, bool SKIP3>
__device__ __forceinline__ void r4s(const float2* __restrict__ src,
                                    float2* __restrict__ dst,
                                    const float2* __restrict__ Wt,
                                    int j){
    const int jm = j & (Ns - 1);
    float2 v0 = src[PHI(j)];
    float2 v1 = src[PHI(j + N4)];
    float2 v2 = src[PHI(j + 2*N4)];
    float2 v3 = make_float2(0.f, 0.f);
    if (!SKIP3) v3 = src[PHI(j + 3*N4)];
    if (Ns > 1){
        const int e = jm * (256 / Ns);   // exponent in W_1024 units (valid for N=1024 and 512)
        float2 w1 = Wt[PHI(e)];
        float2 w2 = Wt[PHI(2*e)];
        float2 w3 = Wt[PHI(3*e)];
        if (INV){ w1.y = -w1.y; w2.y = -w2.y; w3.y = -w3.y; }
        v1 = cmul(v1, w1);
        v2 = cmul(v2, w2);
        if (!SKIP3) v3 = cmul(v3, w3);
    }
    float2 t0 = make_float2(v0.x + v2.x, v0.y + v2.y);
    float2 t1 = make_float2(v0.x - v2.x, v0.y - v2.y);
    float2 t2, t3;
    if (SKIP3){ t2 = v1; t3 = v1; }
    else {
        t2 = make_float2(v1.x + v3.x, v1.y + v3.y);
        t3 = make_float2(v1.x - v3.x, v1.y - v3.y);
    }
    float2 o0 = make_float2(t0.x + t2.x, t0.y + t2.y);
    float2 o2 = make_float2(t0.x - t2.x, t0.y - t2.y);
    float2 o1, o3;
    if (!INV){
        o1 = make_float2(t1.x + t3.y, t1.y - t3.x);
        o3 = make_float2(t1.x - t3.y, t1.y + t3.x);
    } else {
        o1 = make_float2(t1.x - t3.y, t1.y + t3.x);
        o3 = make_float2(t1.x + t3.y, t1.y - t3.x);
    }
    const int base = ((j - jm) << 2) + jm;
    dst[PHI(base)]          = o0;
    dst[PHI(base + Ns)]     = o1;
    dst[PHI(base + 2*Ns)]   = o2;
    dst[PHI(base + 3*Ns)]   = o3;
}

// -------- per-(b,t): packed fwd FFT(1024) -> G (Hermitian) -> real-IFFT via 512 -> window --------
__global__ __launch_bounds__(256) void k_filter(const float* __restrict__ ccep,
                                                const float* __restrict__ z,
                                                float* __restrict__ zw){
    __shared__ __align__(16) float2 A[1152];
    __shared__ __align__(16) float2 Bb[1152];
    __shared__ __align__(16) float2 Wt[872];   // W_1024^k, k<768, PHI-padded
    const int t = blockIdx.x;
    const int b = blockIdx.y;
    const int tid = threadIdx.x;
    const float PI2 = 6.283185307179586f;

    // twiddle table (3 sincos per thread)
    for (int j = tid; j < 768; j += 256){
        float s, c;
        __sincosf(-PI2 * (float)j * (1.0f/1024.0f), &s, &c);
        Wt[PHI(j)] = make_float2(c, s);
    }
    // packed load: p[i] = ccep_pad[i] + i*frame_pad[i]
    const float* crow = &ccep[(b*T_LEN + t)*CSTRIDE];
    #pragma unroll
    for (int r = 0; r < 4; ++r){
        int i = tid + (r << 8);
        float av = (i >= 401 && i < 623) ? crow[i - 401] : 0.f;
        float fv = 0.f;
        if (i < 512){
            int zi = t*HOPSZ + i - 255;
            fv = (zi >= 0 && zi < ZLEN) ? z[b*ZLEN + zi] : 0.f;
        }
        A[PHI(i)] = make_float2(av, fv);
    }
    __syncthreads();

    // forward 1024-pt FFT (input zero on [768,1024) -> SKIP3 in stage 1); result in Bb
    r4s<256,1,  false,true >(A,  Bb, Wt, tid); __syncthreads();
    r4s<256,4,  false,false>(Bb, A,  Wt, tid); __syncthreads();
    r4s<256,16, false,false>(A,  Bb, Wt, tid); __syncthreads();
    r4s<256,64, false,false>(Bb, A,  Wt, tid); __syncthreads();
    r4s<256,256,false,false>(A,  Bb, Wt, tid); __syncthreads();

    // G[k] = conj(F[k])*H[k] for k in [0,512] (G is Hermitian); store into A
    const float LOG2_10_DIV10 = 0.33219280948873623f;
    #pragma unroll
    for (int r = 0; r < 3; ++r){
        int i = tid + (r << 8);
        if (r == 2 && tid != 0) break;   // only k=512 extra
        if (r == 2) i = 512;
        float2 P = Bb[PHI(i)];
        float2 Q = Bb[PHI((1024 - i) & 1023)];
        float Are = 0.5f * (P.x + Q.x);
        float Aim = 0.5f * (P.y - Q.y);
        float Fx  = 0.5f * (P.y + Q.y);
        float Fy  = 0.5f * (Q.x - P.x);
        float mag = exp2f(Are * LOG2_10_DIV10) * (1.0f/1024.0f);
        float s, c;
        sincosf(Aim, &s, &c);
        float Hx = mag * c, Hy = mag * s;
        A[PHI(i)] = make_float2(Fx*Hx + Fy*Hy, Fx*Hy - Fy*Hx);
    }
    __syncthreads();

    // Z'[k] = 2*Z[k] = (G[k]+conj(G[512-k])) + i*(G[k]-conj(G[512-k]))*conj(W^k)
    // (factor 2 compensates the M/N = 1/2 scale of the unnormalized size-512 inverse)
    #pragma unroll
    for (int r = 0; r < 2; ++r){
        int k = tid + (r << 8);
        float2 G  = A[PHI(k)];
        float2 Gp = A[PHI(512 - k)];
        float sx = G.x + Gp.x, sy = G.y - Gp.y;
        float dx = G.x - Gp.x, dy = G.y + Gp.y;
        float2 V = Wt[PHI(k)];
        // u = (dx,dy) * (V.x, -V.y)
        float ux = dx*V.x + dy*V.y;
        float uy = dy*V.x - dx*V.y;
        Bb[PHI(k)] = make_float2(sx - uy, sy + ux);
    }
    __syncthreads();

    // inverse 512-pt FFT: 4 radix-4 stages (128 bf) + final radix-2 (256 bf); z lands in A
    if (tid < 128) r4s<128,1, true,false>(Bb, A,  Wt, tid);
    __syncthreads();
    if (tid < 128) r4s<128,4, true,false>(A,  Bb, Wt, tid);
    __syncthreads();
    if (tid < 128) r4s<128,16,true,false>(Bb, A,  Wt, tid);
    __syncthreads();
    if (tid < 128) r4s<128,64,true,false>(A,  Bb, Wt, tid);
    __syncthreads();
    {
        int j = tid;                       // radix-2, Ns=256: tw = W_512^j = W_1024^(2j)
        float2 u = Bb[PHI(j)];
        float2 v = Bb[PHI(j + 256)];
        float2 w = Wt[PHI(2*j)];
        w.y = -w.y;                        // inverse
        float2 vv = cmul(v, w);
        A[PHI(j)]       = make_float2(u.x + vv.x, u.y + vv.y);
        A[PHI(j + 256)] = make_float2(u.x - vv.x, u.y - vv.y);
    }
    __syncthreads();

    // zw[n] = y[511-n]*hann[n];  y[2m]=Re z[m], y[2m+1]=Im z[m]  ->  m=(511-n)>>1
    float* zrow = &zw[(size_t)(b*T_LEN + t)*512];
    #pragma unroll
    for (int r = 0; r < 2; ++r){
        int n = tid + (r << 8);
        int m = (511 - n) >> 1;
        float2 zv = A[PHI(m)];
        float yv = (n & 1) ? zv.x : zv.y;
        float wv = 0.5f * (1.0f - __cosf(PI2 * (float)n * (1.0f/512.0f)));
        zrow[n] = yv * wv;
    }
}

// -------- OLA + clip --------
__global__ __launch_bounds__(256) void k_ola(const float* __restrict__ zw,
                                             float* __restrict__ out){
    const int t = blockIdx.x;
    const int b = blockIdx.y;
    const int h = threadIdx.x;
    const int tm = (t + T_LEN - 1) % T_LEN;
    float v = zw[(size_t)(b*T_LEN + t)*512 + h]
            + zw[(size_t)(b*T_LEN + tm)*512 + 256 + h];
    v = fminf(fmaxf(v, -1.0f), 1.0f);
    out[(size_t)b*ZLEN + t*HOPSZ + h] = v;
}

extern "C" void kernel_launch(void* const* d_in, const int* in_sizes, int n_in,
                              void* d_out, int out_size, void* d_ws, size_t ws_size,
                              hipStream_t stream){
    const float* x  = (const float*)d_in[0];
    const float* z  = (const float*)d_in[1];
    const float* W1 = (const float*)d_in[2];
    const float* b1 = (const float*)d_in[3];
    const float* W2 = (const float*)d_in[4];
    const float* b2 = (const float*)d_in[5];
    const float* W3 = (const float*)d_in[6];
    const float* b3 = (const float*)d_in[7];
    const float* W4 = (const float*)d_in[8];
    const float* b4 = (const float*)d_in[9];
    float* out = (float*)d_out;
    float* ws  = (float*)d_ws;

    float* h1   = ws;                 // 3,276,800 floats (becomes h3 bf16 planes after conv3)
    float* h2   = ws + 3276800;       // 3,276,800 floats (ccep overlays, 12800*256)
    float* ccep = h2;
    float* zwb  = ws + 6553600;       // 6,553,600 floats
    __hip_bfloat16* h3hi = (__hip_bfloat16*)h1;
    __hip_bfloat16* h3lo = h3hi + 3276800;
    float4* w1t = (float4*)(zwb);                         // 20480 f4
    float4* w2t = (float4*)(zwb + 81920);                 //  8192 f4
    float4* w3t = (float4*)(zwb + 114688);                //  8192 f4
    __hip_bfloat16* wfhi = (__hip_bfloat16*)(zwb + 147456);  // 196608 bf16
    __hip_bfloat16* wflo = wfhi + 196608;

    dim3 blk(256);
    dim3 gwt(768, 4);
    dim3 gconv(T_LEN/16, B_SZ);       // (50,16)
    dim3 gc4(400, 2);
    dim3 gf(T_LEN, B_SZ);             // (800,16)

    k_wtrans<<<gwt, blk, 0, stream>>>(W1, W2, W3, W4, w1t, w2t, w3t, wfhi, wflo);
    k_conv1<<<gconv, blk, 0, stream>>>(x, w1t, b1, h1);
    k_convg<<<gconv, blk, 0, stream>>>(h1, w2t, b2, h2);
    k_convg_bf16<<<gconv, blk, 0, stream>>>(h2, w3t, b3, h3hi, h3lo);
    k_conv4<<<gc4, blk, 0, stream>>>(h3hi, h3lo, wfhi, wflo, b4, ccep);
    k_filter<<<gf, blk, 0, stream>>>(ccep, z, zwb);
    k_ola<<<gf, blk, 0, stream>>>(zwb, out);
}

// Round 13
// 161.318 us; speedup vs baseline: 1.5707x; 1.0897x over previous
//
#include <hip/hip_runtime.h>
#include <hip/hip_bf16.h>

#define T_LEN 800
#define B_SZ  16
#define D_IN  80
#define CCH   256
#define OUT_CH 222
#define HOPSZ 256
#define WINSZ 512
#define ZLEN  (T_LEN*HOPSZ)   // 204800
#define CSTRIDE 256           // ccep row stride ([t][co] layout)

#define PHI(i) ((i) + ((i)>>3))

typedef short short8 __attribute__((ext_vector_type(8)));
typedef float f32x4 __attribute__((ext_vector_type(4)));

__device__ __forceinline__ float2 cmul(float2 a, float2 b){
    return make_float2(a.x*b.x - a.y*b.y, a.x*b.y + a.y*b.x);
}

// -------- weight transpose: float4 [ci][co] for conv1-3; split-bf16 fragment layout for conv4 --------
__global__ __launch_bounds__(256) void k_wtrans(const float* __restrict__ W1,
                                                const float* __restrict__ W2,
                                                const float* __restrict__ W3,
                                                const float* __restrict__ W4,
                                                float4* __restrict__ w1t,
                                                float4* __restrict__ w2t,
                                                float4* __restrict__ w3t,
                                                __hip_bfloat16* __restrict__ wfhi,
                                                __hip_bfloat16* __restrict__ wflo){
    const int i = blockIdx.x*256 + threadIdx.x;
    switch (blockIdx.y){
    case 0: if (i < 80*256){
        int ci = i >> 8, co = i & 255;
        const float* s = &W1[(co*80 + ci)*3];
        w1t[i] = make_float4(s[0], s[1], s[2], 0.f);
    } break;
    case 1: if (i < 32*256){
        int cil = i >> 8, co = i & 255;
        const float* s = &W2[(co*32 + cil)*3];
        w2t[i] = make_float4(s[0], s[1], s[2], 0.f);
    } break;
    case 2: if (i < 32*256){
        int cil = i >> 8, co = i & 255;
        const float* s = &W3[(co*32 + cil)*3];
        w3t[i] = make_float4(s[0], s[1], s[2], 0.f);
    } break;
    default: if (i < 768*256){
        int k = i >> 8, co = i & 255;
        int d = k >> 8, ci = k & 255;
        float w = 0.f;
        if (co < OUT_CH){
            float q = (co < 111) ? (float)(111 - co) : (float)(co - 110);
            w = W4[(co*256 + ci)*3 + d] / q;   // fold 1/quef into weights
        }
        __hip_bfloat16 h = __float2bfloat16(w);
        __hip_bfloat16 l = __float2bfloat16(w - __bfloat162float(h));
        int kt = k >> 5, g = (k >> 3) & 3, e = k & 7;
        int idx = ((kt*4 + g)*256 + co)*8 + e;
        wfhi[idx] = h;
        wflo[idx] = l;
    } break;
    }
}

// -------- conv1: x (B,T,80) -> h1 (B,T,256) [t][c], relu --------
__global__ __launch_bounds__(256) void k_conv1(const float* __restrict__ x,
                                               const float4* __restrict__ Wt,
                                               const float* __restrict__ bias,
                                               float* __restrict__ out){
    __shared__ __align__(16) float xs[80*20];
    const int t0 = blockIdx.x * 16;
    const int b  = blockIdx.y;
    const int tid = threadIdx.x;
    const int co = tid;
    for (int i = tid; i < 80*18; i += 256){
        int tt = i / 80, ci = i - tt*80;
        int t = t0 - 1 + tt;
        xs[ci*20 + tt] = (t >= 0 && t < T_LEN) ? x[(b*T_LEN + t)*D_IN + ci] : 0.f;
    }
    __syncthreads();
    float acc[16];
    float bv = bias[co];
    #pragma unroll
    for (int t = 0; t < 16; ++t) acc[t] = bv;
    const float4* wp = Wt + co;
    float4 w = *wp;
    for (int ci = 0; ci < 80; ++ci){
        wp += 256;
        float4 wn = *wp;   // prefetch; overrun lands in adjacent weight buffer, unused
        const float* xp = &xs[ci*20];
        float4 v0 = *(const float4*)(xp);
        float4 v1 = *(const float4*)(xp + 4);
        float4 v2 = *(const float4*)(xp + 8);
        float4 v3 = *(const float4*)(xp + 12);
        float2 v4 = *(const float2*)(xp + 16);
        float xr[18] = {v0.x,v0.y,v0.z,v0.w, v1.x,v1.y,v1.z,v1.w,
                        v2.x,v2.y,v2.z,v2.w, v3.x,v3.y,v3.z,v3.w, v4.x,v4.y};
        #pragma unroll
        for (int t = 0; t < 16; ++t){
            acc[t] = fmaf(xr[t],   w.x, acc[t]);
            acc[t] = fmaf(xr[t+1], w.y, acc[t]);
            acc[t] = fmaf(xr[t+2], w.z, acc[t]);
        }
        w = wn;
    }
    #pragma unroll
    for (int t = 0; t < 16; ++t)
        out[(b*T_LEN + t0 + t)*CCH + co] = fmaxf(acc[t], 0.f);
}

// -------- fused conv2+conv3 (groups=8): h1 -> (conv2,relu) -> (conv3,relu) -> bf16 planes --------
__global__ __launch_bounds__(256) void k_convg23(const float* __restrict__ in,
                                                 const float4* __restrict__ W2t,
                                                 const float* __restrict__ b2,
                                                 const float4* __restrict__ W3t,
                                                 const float* __restrict__ b3,
                                                 __hip_bfloat16* __restrict__ ohi,
                                                 __hip_bfloat16* __restrict__ olo){
    __shared__ __align__(16) float hs[256*20];
    const int t0 = blockIdx.x * 16;
    const int b  = blockIdx.y;
    const int tid = threadIdx.x;
    const int co = tid;
    const int gbase = (co >> 5) << 5;
    // stage h1 rows [t0-2, t0+18) : 20 t-values
    for (int i = tid; i < 256*20; i += 256){
        int tt = i >> 8, ci = i & 255;
        int t = t0 - 2 + tt;
        hs[ci*20 + tt] = (t >= 0 && t < T_LEN) ? in[(b*T_LEN + t)*CCH + ci] : 0.f;
    }
    __syncthreads();
    // conv2 on 18 t-values (local j=0..17 ~ t=t0-1+j)
    float acc[18];
    {
        float bv = b2[co];
        #pragma unroll
        for (int j = 0; j < 18; ++j) acc[j] = bv;
        const float4* wp = W2t + co;
        float4 w = *wp;
        for (int cil = 0; cil < 32; ++cil){
            wp += 256;
            float4 wn = *wp;   // overrun lands in w3t, unused
            const float* xp = &hs[(gbase + cil)*20];
            float4 v0 = *(const float4*)(xp);
            float4 v1 = *(const float4*)(xp + 4);
            float4 v2 = *(const float4*)(xp + 8);
            float4 v3 = *(const float4*)(xp + 12);
            float4 v4 = *(const float4*)(xp + 16);
            float xr[20] = {v0.x,v0.y,v0.z,v0.w, v1.x,v1.y,v1.z,v1.w,
                            v2.x,v2.y,v2.z,v2.w, v3.x,v3.y,v3.z,v3.w,
                            v4.x,v4.y,v4.z,v4.w};
            #pragma unroll
            for (int j = 0; j < 18; ++j){
                acc[j] = fmaf(xr[j],   w.x, acc[j]);
                acc[j] = fmaf(xr[j+1], w.y, acc[j]);
                acc[j] = fmaf(xr[j+2], w.z, acc[j]);
            }
            w = wn;
        }
    }
    __syncthreads();
    // write conv2 results back into hs; MASK t outside [0,800) to match reference zero-pad
    #pragma unroll
    for (int j = 0; j < 18; ++j){
        int t = t0 - 1 + j;
        hs[co*20 + j] = (t >= 0 && t < T_LEN) ? fmaxf(acc[j], 0.f) : 0.f;
    }
    __syncthreads();
    // conv3 on 16 t-values
    float acc3[16];
    {
        float bv = b3[co];
        #pragma unroll
        for (int j = 0; j < 16; ++j) acc3[j] = bv;
        const float4* wp = W3t + co;
        float4 w = *wp;
        for (int cil = 0; cil < 32; ++cil){
            wp += 256;
            float4 wn = *wp;   // overrun lands in wfhi, unused
            const float* xp = &hs[(gbase + cil)*20];
            float4 v0 = *(const float4*)(xp);
            float4 v1 = *(const float4*)(xp + 4);
            float4 v2 = *(const float4*)(xp + 8);
            float4 v3 = *(const float4*)(xp + 12);
            float2 v4 = *(const float2*)(xp + 16);
            float xr[18] = {v0.x,v0.y,v0.z,v0.w, v1.x,v1.y,v1.z,v1.w,
                            v2.x,v2.y,v2.z,v2.w, v3.x,v3.y,v3.z,v3.w, v4.x,v4.y};
            #pragma unroll
            for (int j = 0; j < 16; ++j){
                acc3[j] = fmaf(xr[j],   w.x, acc3[j]);
                acc3[j] = fmaf(xr[j+1], w.y, acc3[j]);
                acc3[j] = fmaf(xr[j+2], w.z, acc3[j]);
            }
            w = wn;
        }
    }
    #pragma unroll
    for (int j = 0; j < 16; ++j){
        float v = fmaxf(acc3[j], 0.f);
        __hip_bfloat16 h = __float2bfloat16(v);
        __hip_bfloat16 l = __float2bfloat16(v - __bfloat162float(h));
        size_t idx = (size_t)(b*T_LEN + t0 + j)*CCH + co;
        ohi[idx] = h;
        olo[idx] = l;
    }
}

// -------- conv4 via MFMA 16x16x32 bf16, split hi/lo (3 passes fused in K loop) --------
__global__ __launch_bounds__(256) void k_conv4(const __hip_bfloat16* __restrict__ hhi,
                                               const __hip_bfloat16* __restrict__ hlo,
                                               const __hip_bfloat16* __restrict__ wfhi,
                                               const __hip_bfloat16* __restrict__ wflo,
                                               const float* __restrict__ bias,
                                               float* __restrict__ ccep){
    __shared__ __align__(16) unsigned char aLds[2][34*512];
    const int gx = blockIdx.x;              // 400 = 16 b * 25 t-tiles
    const int b  = gx / 25;
    const int t0 = (gx - b*25) * 32;
    const int coBase = blockIdx.y << 7;     // 0 or 128
    const int tid = threadIdx.x;
    const int wave = tid >> 6;
    const int l = tid & 63;
    const int l15 = l & 15, lg = l >> 4;

    for (int i = tid; i < 2*1088; i += 256){
        int p = (i >= 1088);
        int c = i - (p ? 1088 : 0);
        int r = c >> 5, c16 = c & 31;
        int t = t0 - 1 + r;
        uint4 v = make_uint4(0u,0u,0u,0u);
        if (t >= 0 && t < T_LEN){
            const __hip_bfloat16* src = (p ? hlo : hhi) + (((size_t)(b*T_LEN + t)) << 8) + (c16 << 3);
            v = *(const uint4*)src;
        }
        int off = (r << 9) + (c16 << 4);
        off ^= (r & 7) << 4;
        *(uint4*)(&aLds[p][off]) = v;
    }
    __syncthreads();

    const int co0 = coBase + (wave << 5);
    f32x4 acc[2][2];
    #pragma unroll
    for (int n = 0; n < 2; ++n){
        int co = co0 + (n << 4) + l15;
        float bq = 0.f;
        if (co < OUT_CH){
            float q = (co < 111) ? (float)(111 - co) : (float)(co - 110);
            bq = bias[co] / q;
        }
        acc[0][n] = f32x4{bq, bq, bq, bq};
        acc[1][n] = f32x4{bq, bq, bq, bq};
    }

    for (int kt = 0; kt < 24; ++kt){
        const int d   = kt >> 3;
        const int cib = (kt & 7) << 6;
        short8 ah[2], al[2];
        #pragma unroll
        for (int m = 0; m < 2; ++m){
            int r = l15 + d + (m << 4);
            int off = (r << 9) + cib + (lg << 4);
            off ^= (r & 7) << 4;
            ah[m] = __builtin_bit_cast(short8, *(const uint4*)(&aLds[0][off]));
            al[m] = __builtin_bit_cast(short8, *(const uint4*)(&aLds[1][off]));
        }
        #pragma unroll
        for (int n = 0; n < 2; ++n){
            int co = co0 + (n << 4) + l15;
            size_t woff = ((size_t)((kt << 2) + lg) << 8) + co;
            short8 bh = __builtin_bit_cast(short8, *(const uint4*)(wfhi + (woff << 3)));
            short8 bl = __builtin_bit_cast(short8, *(const uint4*)(wflo + (woff << 3)));
            #pragma unroll
            for (int m = 0; m < 2; ++m){
                acc[m][n] = __builtin_amdgcn_mfma_f32_16x16x32_bf16(ah[m], bh, acc[m][n], 0, 0, 0);
                acc[m][n] = __builtin_amdgcn_mfma_f32_16x16x32_bf16(ah[m], bl, acc[m][n], 0, 0, 0);
                acc[m][n] = __builtin_amdgcn_mfma_f32_16x16x32_bf16(al[m], bh, acc[m][n], 0, 0, 0);
            }
        }
    }

    #pragma unroll
    for (int m = 0; m < 2; ++m){
        #pragma unroll
        for (int n = 0; n < 2; ++n){
            int co = co0 + (n << 4) + l15;
            #pragma unroll
            for (int j = 0; j < 4; ++j){
                int t = t0 + (m << 4) + (lg << 2) + j;
                ccep[((size_t)(b*T_LEN + t) << 8) + co] = acc[m][n][j];
            }
        }
    }
}

// -------- radix-4 Stockham stage (N4 = N/4 butterflies; twiddles from 768-entry table) --------
template<int N4, int Ns, bool INV, bool SKIP3>
__device__ __forceinline__ void r4s(const float2* __restrict__ src,
                                    float2* __restrict__ dst,
                                    const float2* __restrict__ Wt,
                                    int j){
    const int jm = j & (Ns - 1);
    float2 v0 = src[PHI(j)];
    float2 v1 = src[PHI(j + N4)];
    float2 v2 = src[PHI(j + 2*N4)];
    float2 v3 = make_float2(0.f, 0.f);
    if (!SKIP3) v3 = src[PHI(j + 3*N4)];
    if (Ns > 1){
        const int e = jm * (256 / Ns);   // exponent in W_1024 units (valid for N=1024 and 512)
        float2 w1 = Wt[PHI(e)];
        float2 w2 = Wt[PHI(2*e)];
        float2 w3 = Wt[PHI(3*e)];
        if (INV){ w1.y = -w1.y; w2.y = -w2.y; w3.y = -w3.y; }
        v1 = cmul(v1, w1);
        v2 = cmul(v2, w2);
        if (!SKIP3) v3 = cmul(v3, w3);
    }
    float2 t0 = make_float2(v0.x + v2.x, v0.y + v2.y);
    float2 t1 = make_float2(v0.x - v2.x, v0.y - v2.y);
    float2 t2, t3;
    if (SKIP3){ t2 = v1; t3 = v1; }
    else {
        t2 = make_float2(v1.x + v3.x, v1.y + v3.y);
        t3 = make_float2(v1.x - v3.x, v1.y - v3.y);
    }
    float2 o0 = make_float2(t0.x + t2.x, t0.y + t2.y);
    float2 o2 = make_float2(t0.x - t2.x, t0.y - t2.y);
    float2 o1, o3;
    if (!INV){
        o1 = make_float2(t1.x + t3.y, t1.y - t3.x);
        o3 = make_float2(t1.x - t3.y, t1.y + t3.x);
    } else {
        o1 = make_float2(t1.x - t3.y, t1.y + t3.x);
        o3 = make_float2(t1.x + t3.y, t1.y - t3.x);
    }
    const int base = ((j - jm) << 2) + jm;
    dst[PHI(base)]          = o0;
    dst[PHI(base + Ns)]     = o1;
    dst[PHI(base + 2*Ns)]   = o2;
    dst[PHI(base + 3*Ns)]   = o3;
}

// -------- per-(b,t): packed fwd FFT(1024) -> merged G/Z-pack -> real-IFFT via 512 -> window --------
__global__ __launch_bounds__(256) void k_filter(const float* __restrict__ ccep,
                                                const float* __restrict__ z,
                                                float* __restrict__ zw){
    __shared__ __align__(16) float2 A[1152];
    __shared__ __align__(16) float2 Bb[1152];
    __shared__ __align__(16) float2 Wt[872];   // W_1024^k, k<768, PHI-padded
    const int t = blockIdx.x;
    const int b = blockIdx.y;
    const int tid = threadIdx.x;
    const float PI2 = 6.283185307179586f;

    for (int j = tid; j < 768; j += 256){
        float s, c;
        __sincosf(-PI2 * (float)j * (1.0f/1024.0f), &s, &c);
        Wt[PHI(j)] = make_float2(c, s);
    }
    const float* crow = &ccep[(b*T_LEN + t)*CSTRIDE];
    #pragma unroll
    for (int r = 0; r < 4; ++r){
        int i = tid + (r << 8);
        float av = (i >= 401 && i < 623) ? crow[i - 401] : 0.f;
        float fv = 0.f;
        if (i < 512){
            int zi = t*HOPSZ + i - 255;
            fv = (zi >= 0 && zi < ZLEN) ? z[b*ZLEN + zi] : 0.f;
        }
        A[PHI(i)] = make_float2(av, fv);
    }
    __syncthreads();

    // forward 1024-pt FFT (input zero on [768,1024) -> SKIP3 in stage 1); result in Bb
    r4s<256,1,  false,true >(A,  Bb, Wt, tid); __syncthreads();
    r4s<256,4,  false,false>(Bb, A,  Wt, tid); __syncthreads();
    r4s<256,16, false,false>(A,  Bb, Wt, tid); __syncthreads();
    r4s<256,64, false,false>(Bb, A,  Wt, tid); __syncthreads();
    r4s<256,256,false,false>(A,  Bb, Wt, tid); __syncthreads();

    // merged: G[k],G[512-k] -> Z'[k],Z'[512-k] written to A (no G round-trip)
    {
        const float LOG2_10_DIV10 = 0.33219280948873623f;
        auto unpackG = [&](int i)->float2 {
            float2 P = Bb[PHI(i)];
            float2 Q = Bb[PHI((1024 - i) & 1023)];
            float Are = 0.5f * (P.x + Q.x);
            float Aim = 0.5f * (P.y - Q.y);
            float Fx  = 0.5f * (P.y + Q.y);
            float Fy  = 0.5f * (Q.x - P.x);
            float mag = exp2f(Are * LOG2_10_DIV10) * (1.0f/1024.0f);
            float s, c;
            __sincosf(Aim, &s, &c);     // |Aim| << 1: fast path safe
            float Hx = mag * c, Hy = mag * s;
            return make_float2(Fx*Hx + Fy*Hy, Fx*Hy - Fy*Hx);
        };
        int k = tid;
        float2 G  = unpackG(k);
        float2 G2 = unpackG(512 - k);
        float sx = G.x + G2.x, sy = G.y - G2.y;
        float dx = G.x - G2.x, dy = G.y + G2.y;
        float2 V = Wt[PHI(k)];
        float ux = dx*V.x + dy*V.y;
        float uy = dy*V.x - dx*V.y;
        A[PHI(k)] = make_float2(sx - uy, sy + ux);            // Z'[k]
        if (k){
            A[PHI(512 - k)] = make_float2(sx + uy, ux - sy);  // Z'[512-k]
        } else {
            float2 G3 = unpackG(256);
            A[PHI(256)] = make_float2(2.f*G3.x, -2.f*G3.y);   // Z'[256]
        }
    }
    __syncthreads();

    // inverse 512-pt FFT: 4 radix-4 stages (128 bf) + final radix-2; z lands in Bb
    if (tid < 128) r4s<128,1, true,false>(A,  Bb, Wt, tid);
    __syncthreads();
    if (tid < 128) r4s<128,4, true,false>(Bb, A,  Wt, tid);
    __syncthreads();
    if (tid < 128) r4s<128,16,true,false>(A,  Bb, Wt, tid);
    __syncthreads();
    if (tid < 128) r4s<128,64,true,false>(Bb, A,  Wt, tid);
    __syncthreads();
    {
        int j = tid;                       // radix-2, Ns=256: tw = W_512^j = W_1024^(2j)
        float2 u = A[PHI(j)];
        float2 v = A[PHI(j + 256)];
        float2 w = Wt[PHI(2*j)];
        w.y = -w.y;                        // inverse
        float2 vv = cmul(v, w);
        Bb[PHI(j)]       = make_float2(u.x + vv.x, u.y + vv.y);
        Bb[PHI(j + 256)] = make_float2(u.x - vv.x, u.y - vv.y);
    }
    __syncthreads();

    // zw[n] = y[511-n]*hann[n];  y[2m]=Re z[m], y[2m+1]=Im z[m]  ->  m=(511-n)>>1
    float* zrow = &zw[(size_t)(b*T_LEN + t)*512];
    #pragma unroll
    for (int r = 0; r < 2; ++r){
        int n = tid + (r << 8);
        int m = (511 - n) >> 1;
        float2 zv = Bb[PHI(m)];
        float yv = (n & 1) ? zv.x : zv.y;
        float wv = 0.5f * (1.0f - __cosf(PI2 * (float)n * (1.0f/512.0f)));
        zrow[n] = yv * wv;
    }
}

// -------- OLA + clip --------
__global__ __launch_bounds__(256) void k_ola(const float* __restrict__ zw,
                                             float* __restrict__ out){
    const int t = blockIdx.x;
    const int b = blockIdx.y;
    const int h = threadIdx.x;
    const int tm = (t + T_LEN - 1) % T_LEN;
    float v = zw[(size_t)(b*T_LEN + t)*512 + h]
            + zw[(size_t)(b*T_LEN + tm)*512 + 256 + h];
    v = fminf(fmaxf(v, -1.0f), 1.0f);
    out[(size_t)b*ZLEN + t*HOPSZ + h] = v;
}

extern "C" void kernel_launch(void* const* d_in, const int* in_sizes, int n_in,
                              void* d_out, int out_size, void* d_ws, size_t ws_size,
                              hipStream_t stream){
    const float* x  = (const float*)d_in[0];
    const float* z  = (const float*)d_in[1];
    const float* W1 = (const float*)d_in[2];
    const float* b1 = (const float*)d_in[3];
    const float* W2 = (const float*)d_in[4];
    const float* b2 = (const float*)d_in[5];
    const float* W3 = (const float*)d_in[6];
    const float* b3 = (const float*)d_in[7];
    const float* W4 = (const float*)d_in[8];
    const float* b4 = (const float*)d_in[9];
    float* out = (float*)d_out;
    float* ws  = (float*)d_ws;

    float* h1   = ws;                 // 3,276,800 floats (h3 planes overlay h2 region below)
    float* h2   = ws + 3276800;       // 3,276,800 floats
    float* ccep = h2;                 // ccep overlays h2? NO: h3 planes live in h2; see below
    float* zwb  = ws + 6553600;       // 6,553,600 floats
    // conv3 bf16 planes go where h2 used to (h2 no longer exists as f32):
    __hip_bfloat16* h3hi = (__hip_bfloat16*)h2;
    __hip_bfloat16* h3lo = h3hi + 3276800;
    // ccep must not overlap h3 planes (conv4 reads planes, writes ccep):
    // planes occupy h2's 13.1MB fully -> put ccep in the TAIL of zwb (zw uses first
    // 6,553,600 floats; ccep needs 3,276,800 -> zwb+? zw IS 6,553,600 floats = all of zwb.
    // Instead: ccep overlays h1 (dead after convg23 consumed it... h1 is read by convg23
    // which runs before conv4 -> safe to overwrite in conv4).
    ccep = h1;
    // weights in FRONT of zwb (read by convs, overwritten later by k_filter)
    float4* w1t = (float4*)(zwb);                         // 20480 f4
    float4* w2t = (float4*)(zwb + 81920);                 //  8192 f4
    float4* w3t = (float4*)(zwb + 114688);                //  8192 f4
    __hip_bfloat16* wfhi = (__hip_bfloat16*)(zwb + 147456);  // 196608 bf16
    __hip_bfloat16* wflo = wfhi + 196608;

    dim3 blk(256);
    dim3 gwt(768, 4);
    dim3 gconv(T_LEN/16, B_SZ);       // (50,16)
    dim3 gc4(400, 2);
    dim3 gf(T_LEN, B_SZ);             // (800,16)

    k_wtrans<<<gwt, blk, 0, stream>>>(W1, W2, W3, W4, w1t, w2t, w3t, wfhi, wflo);
    k_conv1<<<gconv, blk, 0, stream>>>(x, w1t, b1, h1);
    k_convg23<<<gconv, blk, 0, stream>>>(h1, w2t, b2, w3t, b3, h3hi, h3lo);
    k_conv4<<<gc4, blk, 0, stream>>>(h3hi, h3lo, wfhi, wflo, b4, ccep);
    k_filter<<<gf, blk, 0, stream>>>(ccep, z, zwb);
    k_ola<<<gf, blk, 0, stream>>>(zwb, out);
}

// Round 14
// 154.115 us; speedup vs baseline: 1.6441x; 1.0467x over previous
//
#include <hip/hip_runtime.h>
#include <hip/hip_bf16.h>

#define T_LEN 800
#define B_SZ  16
#define D_IN  80
#define CCH   256
#define OUT_CH 222
#define HOPSZ 256
#define WINSZ 512
#define ZLEN  (T_LEN*HOPSZ)   // 204800
#define CSTRIDE 256           // ccep row stride ([t][co] layout)

#define PHI(i) ((i) + ((i)>>3))

typedef short short8 __attribute__((ext_vector_type(8)));
typedef float f32x4 __attribute__((ext_vector_type(4)));

__device__ __forceinline__ float2 cmul(float2 a, float2 b){
    return make_float2(a.x*b.x - a.y*b.y, a.x*b.y + a.y*b.x);
}

// -------- weight transpose: float4 [ci][co] for conv1-3; split-bf16 fragment layout for conv4 --------
__global__ __launch_bounds__(256) void k_wtrans(const float* __restrict__ W1,
                                                const float* __restrict__ W2,
                                                const float* __restrict__ W3,
                                                const float* __restrict__ W4,
                                                float4* __restrict__ w1t,
                                                float4* __restrict__ w2t,
                                                float4* __restrict__ w3t,
                                                __hip_bfloat16* __restrict__ wfhi,
                                                __hip_bfloat16* __restrict__ wflo){
    const int i = blockIdx.x*256 + threadIdx.x;
    switch (blockIdx.y){
    case 0: if (i < 80*256){
        int ci = i >> 8, co = i & 255;
        const float* s = &W1[(co*80 + ci)*3];
        w1t[i] = make_float4(s[0], s[1], s[2], 0.f);
    } break;
    case 1: if (i < 32*256){
        int cil = i >> 8, co = i & 255;
        const float* s = &W2[(co*32 + cil)*3];
        w2t[i] = make_float4(s[0], s[1], s[2], 0.f);
    } break;
    case 2: if (i < 32*256){
        int cil = i >> 8, co = i & 255;
        const float* s = &W3[(co*32 + cil)*3];
        w3t[i] = make_float4(s[0], s[1], s[2], 0.f);
    } break;
    default: if (i < 768*256){
        int k = i >> 8, co = i & 255;
        int d = k >> 8, ci = k & 255;
        float w = 0.f;
        if (co < OUT_CH){
            float q = (co < 111) ? (float)(111 - co) : (float)(co - 110);
            w = W4[(co*256 + ci)*3 + d] / q;   // fold 1/quef into weights
        }
        __hip_bfloat16 h = __float2bfloat16(w);
        __hip_bfloat16 l = __float2bfloat16(w - __bfloat162float(h));
        int kt = k >> 5, g = (k >> 3) & 3, e = k & 7;
        int idx = ((kt*4 + g)*256 + co)*8 + e;
        wfhi[idx] = h;
        wflo[idx] = l;
    } break;
    }
}

// -------- fused conv1+conv2+conv3: x -> bf16 hi/lo planes --------
__global__ __launch_bounds__(256) void k_conv123(const float* __restrict__ x,
                                                 const float4* __restrict__ W1t,
                                                 const float* __restrict__ b1,
                                                 const float4* __restrict__ W2t,
                                                 const float* __restrict__ b2,
                                                 const float4* __restrict__ W3t,
                                                 const float* __restrict__ b3,
                                                 __hip_bfloat16* __restrict__ ohi,
                                                 __hip_bfloat16* __restrict__ olo){
    __shared__ __align__(16) float xs[80*24];    // x rows [t0-3, t0+19), stride 24
    __shared__ __align__(16) float hs[256*20];   // conv1/conv2 results, stride 20
    const int t0 = blockIdx.x * 16;
    const int b  = blockIdx.y;
    const int tid = threadIdx.x;
    const int co = tid;
    const int gbase = (co >> 5) << 5;
    // stage x: 22 t-values x 80 ci
    for (int i = tid; i < 80*22; i += 256){
        int tt = i / 80, ci = i - tt*80;
        int t = t0 - 3 + tt;
        xs[ci*24 + tt] = (t >= 0 && t < T_LEN) ? x[(b*T_LEN + t)*D_IN + ci] : 0.f;
    }
    __syncthreads();
    // conv1: 20 outputs (t = t0-2+jj, jj=0..19)
    {
        float acc[20];
        float bv = b1[co];
        #pragma unroll
        for (int j = 0; j < 20; ++j) acc[j] = bv;
        const float4* wp = W1t + co;
        float4 w = *wp;
        for (int ci = 0; ci < 80; ++ci){
            wp += 256;
            float4 wn = *wp;   // overrun lands in w2t, unused
            const float* xp = &xs[ci*24];
            float4 v0 = *(const float4*)(xp);
            float4 v1 = *(const float4*)(xp + 4);
            float4 v2 = *(const float4*)(xp + 8);
            float4 v3 = *(const float4*)(xp + 12);
            float4 v4 = *(const float4*)(xp + 16);
            float2 v5 = *(const float2*)(xp + 20);
            float xr[22] = {v0.x,v0.y,v0.z,v0.w, v1.x,v1.y,v1.z,v1.w,
                            v2.x,v2.y,v2.z,v2.w, v3.x,v3.y,v3.z,v3.w,
                            v4.x,v4.y,v4.z,v4.w, v5.x,v5.y};
            #pragma unroll
            for (int j = 0; j < 20; ++j){
                acc[j] = fmaf(xr[j],   w.x, acc[j]);
                acc[j] = fmaf(xr[j+1], w.y, acc[j]);
                acc[j] = fmaf(xr[j+2], w.z, acc[j]);
            }
            w = wn;
        }
        // write relu(conv1), masked outside [0,800) (matches reference zero-pad)
        #pragma unroll
        for (int j = 0; j < 20; ++j){
            int t = t0 - 2 + j;
            hs[co*20 + j] = (t >= 0 && t < T_LEN) ? fmaxf(acc[j], 0.f) : 0.f;
        }
    }
    __syncthreads();
    // conv2: 18 outputs (t = t0-1+j)
    float acc2[18];
    {
        float bv = b2[co];
        #pragma unroll
        for (int j = 0; j < 18; ++j) acc2[j] = bv;
        const float4* wp = W2t + co;
        float4 w = *wp;
        for (int cil = 0; cil < 32; ++cil){
            wp += 256;
            float4 wn = *wp;   // overrun lands in w3t, unused
            const float* xp = &hs[(gbase + cil)*20];
            float4 v0 = *(const float4*)(xp);
            float4 v1 = *(const float4*)(xp + 4);
            float4 v2 = *(const float4*)(xp + 8);
            float4 v3 = *(const float4*)(xp + 12);
            float4 v4 = *(const float4*)(xp + 16);
            float xr[20] = {v0.x,v0.y,v0.z,v0.w, v1.x,v1.y,v1.z,v1.w,
                            v2.x,v2.y,v2.z,v2.w, v3.x,v3.y,v3.z,v3.w,
                            v4.x,v4.y,v4.z,v4.w};
            #pragma unroll
            for (int j = 0; j < 18; ++j){
                acc2[j] = fmaf(xr[j],   w.x, acc2[j]);
                acc2[j] = fmaf(xr[j+1], w.y, acc2[j]);
                acc2[j] = fmaf(xr[j+2], w.z, acc2[j]);
            }
            w = wn;
        }
    }
    __syncthreads();
    #pragma unroll
    for (int j = 0; j < 18; ++j){
        int t = t0 - 1 + j;
        hs[co*20 + j] = (t >= 0 && t < T_LEN) ? fmaxf(acc2[j], 0.f) : 0.f;
    }
    __syncthreads();
    // conv3: 16 outputs
    float acc3[16];
    {
        float bv = b3[co];
        #pragma unroll
        for (int j = 0; j < 16; ++j) acc3[j] = bv;
        const float4* wp = W3t + co;
        float4 w = *wp;
        for (int cil = 0; cil < 32; ++cil){
            wp += 256;
            float4 wn = *wp;   // overrun lands in wfhi, unused
            const float* xp = &hs[(gbase + cil)*20];
            float4 v0 = *(const float4*)(xp);
            float4 v1 = *(const float4*)(xp + 4);
            float4 v2 = *(const float4*)(xp + 8);
            float4 v3 = *(const float4*)(xp + 12);
            float2 v4 = *(const float2*)(xp + 16);
            float xr[18] = {v0.x,v0.y,v0.z,v0.w, v1.x,v1.y,v1.z,v1.w,
                            v2.x,v2.y,v2.z,v2.w, v3.x,v3.y,v3.z,v3.w, v4.x,v4.y};
            #pragma unroll
            for (int j = 0; j < 16; ++j){
                acc3[j] = fmaf(xr[j],   w.x, acc3[j]);
                acc3[j] = fmaf(xr[j+1], w.y, acc3[j]);
                acc3[j] = fmaf(xr[j+2], w.z, acc3[j]);
            }
            w = wn;
        }
    }
    #pragma unroll
    for (int j = 0; j < 16; ++j){
        float v = fmaxf(acc3[j], 0.f);
        __hip_bfloat16 h = __float2bfloat16(v);
        __hip_bfloat16 l = __float2bfloat16(v - __bfloat162float(h));
        size_t idx = (size_t)(b*T_LEN + t0 + j)*CCH + co;
        ohi[idx] = h;
        olo[idx] = l;
    }
}

// -------- conv4 via MFMA 16x16x32 bf16, split hi/lo (3 passes fused in K loop) --------
__global__ __launch_bounds__(256) void k_conv4(const __hip_bfloat16* __restrict__ hhi,
                                               const __hip_bfloat16* __restrict__ hlo,
                                               const __hip_bfloat16* __restrict__ wfhi,
                                               const __hip_bfloat16* __restrict__ wflo,
                                               const float* __restrict__ bias,
                                               float* __restrict__ ccep){
    __shared__ __align__(16) unsigned char aLds[2][34*512];
    const int gx = blockIdx.x;              // 400 = 16 b * 25 t-tiles
    const int b  = gx / 25;
    const int t0 = (gx - b*25) * 32;
    const int coBase = blockIdx.y << 7;     // 0 or 128
    const int tid = threadIdx.x;
    const int wave = tid >> 6;
    const int l = tid & 63;
    const int l15 = l & 15, lg = l >> 4;

    for (int i = tid; i < 2*1088; i += 256){
        int p = (i >= 1088);
        int c = i - (p ? 1088 : 0);
        int r = c >> 5, c16 = c & 31;
        int t = t0 - 1 + r;
        uint4 v = make_uint4(0u,0u,0u,0u);
        if (t >= 0 && t < T_LEN){
            const __hip_bfloat16* src = (p ? hlo : hhi) + (((size_t)(b*T_LEN + t)) << 8) + (c16 << 3);
            v = *(const uint4*)src;
        }
        int off = (r << 9) + (c16 << 4);
        off ^= (r & 7) << 4;
        *(uint4*)(&aLds[p][off]) = v;
    }
    __syncthreads();

    const int co0 = coBase + (wave << 5);
    f32x4 acc[2][2];
    #pragma unroll
    for (int n = 0; n < 2; ++n){
        int co = co0 + (n << 4) + l15;
        float bq = 0.f;
        if (co < OUT_CH){
            float q = (co < 111) ? (float)(111 - co) : (float)(co - 110);
            bq = bias[co] / q;
        }
        acc[0][n] = f32x4{bq, bq, bq, bq};
        acc[1][n] = f32x4{bq, bq, bq, bq};
    }

    for (int kt = 0; kt < 24; ++kt){
        const int d   = kt >> 3;
        const int cib = (kt & 7) << 6;
        short8 ah[2], al[2];
        #pragma unroll
        for (int m = 0; m < 2; ++m){
            int r = l15 + d + (m << 4);
            int off = (r << 9) + cib + (lg << 4);
            off ^= (r & 7) << 4;
            ah[m] = __builtin_bit_cast(short8, *(const uint4*)(&aLds[0][off]));
            al[m] = __builtin_bit_cast(short8, *(const uint4*)(&aLds[1][off]));
        }
        #pragma unroll
        for (int n = 0; n < 2; ++n){
            int co = co0 + (n << 4) + l15;
            size_t woff = ((size_t)((kt << 2) + lg) << 8) + co;
            short8 bh = __builtin_bit_cast(short8, *(const uint4*)(wfhi + (woff << 3)));
            short8 bl = __builtin_bit_cast(short8, *(const uint4*)(wflo + (woff << 3)));
            #pragma unroll
            for (int m = 0; m < 2; ++m){
                acc[m][n] = __builtin_amdgcn_mfma_f32_16x16x32_bf16(ah[m], bh, acc[m][n], 0, 0, 0);
                acc[m][n] = __builtin_amdgcn_mfma_f32_16x16x32_bf16(ah[m], bl, acc[m][n], 0, 0, 0);
                acc[m][n] = __builtin_amdgcn_mfma_f32_16x16x32_bf16(al[m], bh, acc[m][n], 0, 0, 0);
            }
        }
    }

    #pragma unroll
    for (int m = 0; m < 2; ++m){
        #pragma unroll
        for (int n = 0; n < 2; ++n){
            int co = co0 + (n << 4) + l15;
            #pragma unroll
            for (int j = 0; j < 4; ++j){
                int t = t0 + (m << 4) + (lg << 2) + j;
                ccep[((size_t)(b*T_LEN + t) << 8) + co] = acc[m][n][j];
            }
        }
    }
}

// -------- radix-4 Stockham stage; w1 from 512-entry table, w2/w3 via cmul --------
template<int N4, int Ns, bool INV, bool SKIP3>
__device__ __forceinline__ void r4s(const float2* __restrict__ src,
                                    float2* __restrict__ dst,
                                    const float2* __restrict__ Wt,
                                    int j){
    const int jm = j & (Ns - 1);
    float2 v0 = src[PHI(j)];
    float2 v1 = src[PHI(j + N4)];
    float2 v2 = src[PHI(j + 2*N4)];
    float2 v3 = make_float2(0.f, 0.f);
    if (!SKIP3) v3 = src[PHI(j + 3*N4)];
    if (Ns > 1){
        const int e = jm * (256 / Ns);   // exponent in W_1024 units (valid for N=1024 and 512)
        float2 w1 = Wt[PHI(e)];
        if (INV) w1.y = -w1.y;
        float2 w2 = cmul(w1, w1);
        float2 w3 = cmul(w2, w1);
        v1 = cmul(v1, w1);
        v2 = cmul(v2, w2);
        if (!SKIP3) v3 = cmul(v3, w3);
    }
    float2 t0 = make_float2(v0.x + v2.x, v0.y + v2.y);
    float2 t1 = make_float2(v0.x - v2.x, v0.y - v2.y);
    float2 t2, t3;
    if (SKIP3){ t2 = v1; t3 = v1; }
    else {
        t2 = make_float2(v1.x + v3.x, v1.y + v3.y);
        t3 = make_float2(v1.x - v3.x, v1.y - v3.y);
    }
    float2 o0 = make_float2(t0.x + t2.x, t0.y + t2.y);
    float2 o2 = make_float2(t0.x - t2.x, t0.y - t2.y);
    float2 o1, o3;
    if (!INV){
        o1 = make_float2(t1.x + t3.y, t1.y - t3.x);
        o3 = make_float2(t1.x - t3.y, t1.y + t3.x);
    } else {
        o1 = make_float2(t1.x - t3.y, t1.y + t3.x);
        o3 = make_float2(t1.x + t3.y, t1.y - t3.x);
    }
    const int base = ((j - jm) << 2) + jm;
    dst[PHI(base)]          = o0;
    dst[PHI(base + Ns)]     = o1;
    dst[PHI(base + 2*Ns)]   = o2;
    dst[PHI(base + 3*Ns)]   = o3;
}

// -------- per-(b,t): packed fwd FFT(1024) -> merged G/Z-pack -> real-IFFT via 512 -> window --------
__global__ __launch_bounds__(256) void k_filter(const float* __restrict__ ccep,
                                                const float* __restrict__ z,
                                                float* __restrict__ zw){
    __shared__ __align__(16) float2 A[1152];
    __shared__ __align__(16) float2 Bb[1152];
    __shared__ __align__(16) float2 Wt[576];   // W_1024^k, k<512, PHI-padded
    const int t = blockIdx.x;
    const int b = blockIdx.y;
    const int tid = threadIdx.x;
    const float PI2 = 6.283185307179586f;

    for (int j = tid; j < 512; j += 256){
        float s, c;
        __sincosf(-PI2 * (float)j * (1.0f/1024.0f), &s, &c);
        Wt[PHI(j)] = make_float2(c, s);
    }
    const float* crow = &ccep[(b*T_LEN + t)*CSTRIDE];
    #pragma unroll
    for (int r = 0; r < 4; ++r){
        int i = tid + (r << 8);
        float av = (i >= 401 && i < 623) ? crow[i - 401] : 0.f;
        float fv = 0.f;
        if (i < 512){
            int zi = t*HOPSZ + i - 255;
            fv = (zi >= 0 && zi < ZLEN) ? z[b*ZLEN + zi] : 0.f;
        }
        A[PHI(i)] = make_float2(av, fv);
    }
    __syncthreads();

    // forward 1024-pt FFT (input zero on [768,1024) -> SKIP3 in stage 1); result in Bb
    r4s<256,1,  false,true >(A,  Bb, Wt, tid); __syncthreads();
    r4s<256,4,  false,false>(Bb, A,  Wt, tid); __syncthreads();
    r4s<256,16, false,false>(A,  Bb, Wt, tid); __syncthreads();
    r4s<256,64, false,false>(Bb, A,  Wt, tid); __syncthreads();
    r4s<256,256,false,false>(A,  Bb, Wt, tid); __syncthreads();

    // merged: G[k],G[512-k] -> Z'[k],Z'[512-k] written to A (no G round-trip)
    {
        const float LOG2_10_DIV10 = 0.33219280948873623f;
        auto unpackG = [&](int i)->float2 {
            float2 P = Bb[PHI(i)];
            float2 Q = Bb[PHI((1024 - i) & 1023)];
            float Are = 0.5f * (P.x + Q.x);
            float Aim = 0.5f * (P.y - Q.y);
            float Fx  = 0.5f * (P.y + Q.y);
            float Fy  = 0.5f * (Q.x - P.x);
            float mag = exp2f(Are * LOG2_10_DIV10) * (1.0f/1024.0f);
            float s, c;
            __sincosf(Aim, &s, &c);     // |Aim| << 1: fast path safe
            float Hx = mag * c, Hy = mag * s;
            return make_float2(Fx*Hx + Fy*Hy, Fx*Hy - Fy*Hx);
        };
        int k = tid;
        float2 G  = unpackG(k);
        float2 G2 = unpackG(512 - k);
        float sx = G.x + G2.x, sy = G.y - G2.y;
        float dx = G.x - G2.x, dy = G.y + G2.y;
        float2 V = Wt[PHI(k)];
        float ux = dx*V.x + dy*V.y;
        float uy = dy*V.x - dx*V.y;
        A[PHI(k)] = make_float2(sx - uy, sy + ux);            // Z'[k]
        if (k){
            A[PHI(512 - k)] = make_float2(sx + uy, ux - sy);  // Z'[512-k]
        } else {
            float2 G3 = unpackG(256);
            A[PHI(256)] = make_float2(2.f*G3.x, -2.f*G3.y);   // Z'[256]
        }
    }
    __syncthreads();

    // inverse 512-pt FFT: 4 radix-4 stages (128 bf) + final radix-2; z lands in Bb
    if (tid < 128) r4s<128,1, true,false>(A,  Bb, Wt, tid);
    __syncthreads();
    if (tid < 128) r4s<128,4, true,false>(Bb, A,  Wt, tid);
    __syncthreads();
    if (tid < 128) r4s<128,16,true,false>(A,  Bb, Wt, tid);
    __syncthreads();
    if (tid < 128) r4s<128,64,true,false>(Bb, A,  Wt, tid);
    __syncthreads();
    {
        int j = tid;                       // radix-2, Ns=256: tw = W_512^j = W_1024^(2j)
        float2 u = A[PHI(j)];
        float2 v = A[PHI(j + 256)];
        float2 w = Wt[PHI(2*j)];
        w.y = -w.y;                        // inverse
        float2 vv = cmul(v, w);
        Bb[PHI(j)]       = make_float2(u.x + vv.x, u.y + vv.y);
        Bb[PHI(j + 256)] = make_float2(u.x - vv.x, u.y - vv.y);
    }
    __syncthreads();

    // zw[n] = y[511-n]*hann[n];  y[2m]=Re z[m], y[2m+1]=Im z[m]  ->  m=(511-n)>>1
    float* zrow = &zw[(size_t)(b*T_LEN + t)*512];
    #pragma unroll
    for (int r = 0; r < 2; ++r){
        int n = tid + (r << 8);
        int m = (511 - n) >> 1;
        float2 zv = Bb[PHI(m)];
        float yv = (n & 1) ? zv.x : zv.y;
        float wv = 0.5f * (1.0f - __cosf(PI2 * (float)n * (1.0f/512.0f)));
        zrow[n] = yv * wv;
    }
}

// -------- OLA + clip --------
__global__ __launch_bounds__(256) void k_ola(const float* __restrict__ zw,
                                             float* __restrict__ out){
    const int t = blockIdx.x;
    const int b = blockIdx.y;
    const int h = threadIdx.x;
    const int tm = (t + T_LEN - 1) % T_LEN;
    float v = zw[(size_t)(b*T_LEN + t)*512 + h]
            + zw[(size_t)(b*T_LEN + tm)*512 + 256 + h];
    v = fminf(fmaxf(v, -1.0f), 1.0f);
    out[(size_t)b*ZLEN + t*HOPSZ + h] = v;
}

extern "C" void kernel_launch(void* const* d_in, const int* in_sizes, int n_in,
                              void* d_out, int out_size, void* d_ws, size_t ws_size,
                              hipStream_t stream){
    const float* x  = (const float*)d_in[0];
    const float* z  = (const float*)d_in[1];
    const float* W1 = (const float*)d_in[2];
    const float* b1 = (const float*)d_in[3];
    const float* W2 = (const float*)d_in[4];
    const float* b2 = (const float*)d_in[5];
    const float* W3 = (const float*)d_in[6];
    const float* b3 = (const float*)d_in[7];
    const float* W4 = (const float*)d_in[8];
    const float* b4 = (const float*)d_in[9];
    float* out = (float*)d_out;
    float* ws  = (float*)d_ws;

    // layout (floats):
    float* ccep = ws;                 // 3,276,800 (written by conv4, read by filter)
    __hip_bfloat16* h3hi = (__hip_bfloat16*)(ws + 3276800);   // conv123 out planes
    __hip_bfloat16* h3lo = h3hi + 3276800;                    // (13.1 MB total)
    float* zwb  = ws + 6553600;       // 6,553,600 floats
    // weights in FRONT of zwb (read by convs, overwritten later by k_filter)
    float4* w1t = (float4*)(zwb);                         // 20480 f4
    float4* w2t = (float4*)(zwb + 81920);                 //  8192 f4
    float4* w3t = (float4*)(zwb + 114688);                //  8192 f4
    __hip_bfloat16* wfhi = (__hip_bfloat16*)(zwb + 147456);  // 196608 bf16
    __hip_bfloat16* wflo = wfhi + 196608;

    dim3 blk(256);
    dim3 gwt(768, 4);
    dim3 gconv(T_LEN/16, B_SZ);       // (50,16)
    dim3 gc4(400, 2);
    dim3 gf(T_LEN, B_SZ);             // (800,16)

    k_wtrans<<<gwt, blk, 0, stream>>>(W1, W2, W3, W4, w1t, w2t, w3t, wfhi, wflo);
    k_conv123<<<gconv, blk, 0, stream>>>(x, w1t, b1, w2t, b2, w3t, b3, h3hi, h3lo);
    k_conv4<<<gc4, blk, 0, stream>>>(h3hi, h3lo, wfhi, wflo, b4, ccep);
    k_filter<<<gf, blk, 0, stream>>>(ccep, z, zwb);
    k_ola<<<gf, blk, 0, stream>>>(zwb, out);
}

// Round 15
// 143.878 us; speedup vs baseline: 1.7611x; 1.0712x over previous
//
#include <hip/hip_runtime.h>
#include <hip/hip_bf16.h>

#define T_LEN 800
#define B_SZ  16
#define D_IN  80
#define CCH   256
#define OUT_CH 222
#define HOPSZ 256
#define WINSZ 512
#define ZLEN  (T_LEN*HOPSZ)   // 204800
#define CSTRIDE 256           // ccep row stride ([t][co] layout)
#define XSTR 104              // bf16 row stride for staged x (2-way-free banks)

#define PHI(i) ((i) + ((i)>>3))

typedef short short8 __attribute__((ext_vector_type(8)));
typedef float f32x4 __attribute__((ext_vector_type(4)));

__device__ __forceinline__ float2 cmul(float2 a, float2 b){
    return make_float2(a.x*b.x - a.y*b.y, a.x*b.y + a.y*b.x);
}

// -------- weight transforms --------
// w2t/w3t: float4 [ci][co].  w1f: conv1 fragment-split, k=ci (pad 80->96),
// idx = (((d*3+kt)*4+lg)*256+co)*8+e with ci = kt*32+lg*8+e.  wf4: conv4 table.
__global__ __launch_bounds__(256) void k_wtrans(const float* __restrict__ W1,
                                                const float* __restrict__ W2,
                                                const float* __restrict__ W3,
                                                const float* __restrict__ W4,
                                                float4* __restrict__ w2t,
                                                float4* __restrict__ w3t,
                                                __hip_bfloat16* __restrict__ w1fhi,
                                                __hip_bfloat16* __restrict__ w1flo,
                                                __hip_bfloat16* __restrict__ wfhi,
                                                __hip_bfloat16* __restrict__ wflo){
    const int i = blockIdx.x*256 + threadIdx.x;
    switch (blockIdx.y){
    case 0: if (i < 32*256){
        int cil = i >> 8, co = i & 255;
        const float* s = &W2[(co*32 + cil)*3];
        w2t[i] = make_float4(s[0], s[1], s[2], 0.f);
    } break;
    case 1: if (i < 32*256){
        int cil = i >> 8, co = i & 255;
        const float* s = &W3[(co*32 + cil)*3];
        w3t[i] = make_float4(s[0], s[1], s[2], 0.f);
    } break;
    case 2: if (i < 9*4*256*8){
        int e  = i & 7;
        int co = (i >> 3) & 255;
        int lg = (i >> 11) & 3;
        int dk = i >> 13;            // 0..8
        int d  = dk / 3, kt = dk - 3*d;
        int ci = kt*32 + lg*8 + e;
        float w = (ci < 80) ? W1[(co*80 + ci)*3 + d] : 0.f;
        __hip_bfloat16 h = __float2bfloat16(w);
        __hip_bfloat16 l = __float2bfloat16(w - __bfloat162float(h));
        w1fhi[i] = h;
        w1flo[i] = l;
    } break;
    default: if (i < 768*256){
        int k = i >> 8, co = i & 255;
        int d = k >> 8, ci = k & 255;
        float w = 0.f;
        if (co < OUT_CH){
            float q = (co < 111) ? (float)(111 - co) : (float)(co - 110);
            w = W4[(co*256 + ci)*3 + d] / q;   // fold 1/quef into weights
        }
        __hip_bfloat16 h = __float2bfloat16(w);
        __hip_bfloat16 l = __float2bfloat16(w - __bfloat162float(h));
        int kt = k >> 5, g = (k >> 3) & 3, e = k & 7;
        int idx = ((kt*4 + g)*256 + co)*8 + e;
        wfhi[idx] = h;
        wflo[idx] = l;
    } break;
    }
}

// -------- fused conv1(MFMA)+conv2+conv3: x -> bf16 hi/lo planes --------
__global__ __launch_bounds__(256) void k_conv123(const float* __restrict__ x,
                                                 const __hip_bfloat16* __restrict__ w1fhi,
                                                 const __hip_bfloat16* __restrict__ w1flo,
                                                 const float* __restrict__ b1,
                                                 const float4* __restrict__ W2t,
                                                 const float* __restrict__ b2,
                                                 const float4* __restrict__ W3t,
                                                 const float* __restrict__ b3,
                                                 __hip_bfloat16* __restrict__ ohi,
                                                 __hip_bfloat16* __restrict__ olo){
    __shared__ __align__(16) __hip_bfloat16 xhi[34*XSTR];  // x rows t0-3..t0+30, split hi
    __shared__ __align__(16) __hip_bfloat16 xlo[34*XSTR];
    __shared__ __align__(16) float hs[256*20];             // [co][t-local]
    const int t0 = blockIdx.x * 16;
    const int b  = blockIdx.y;
    const int tid = threadIdx.x;
    const int co = tid;
    const int gbase = (co >> 5) << 5;
    const int wave = tid >> 6;
    const int l = tid & 63;
    const int l15 = l & 15, lg4 = l >> 4;

    // stage x as split bf16; pad columns [80,104) zeroed (A pad reads × W zeros)
    for (int i = tid; i < 34*XSTR; i += 256){
        int rr = i / XSTR, c = i - rr*XSTR;
        float v = 0.f;
        if (c < 80){
            int t = t0 - 3 + rr;
            v = (t >= 0 && t < T_LEN) ? x[(b*T_LEN + t)*D_IN + c] : 0.f;
        }
        __hip_bfloat16 h = __float2bfloat16(v);
        xhi[i] = h;
        xlo[i] = __float2bfloat16(v - __bfloat162float(h));
    }
    __syncthreads();

    // conv1 via MFMA: C[trow][co] = sum_d sum_ci x[trow+d][ci] * W1[d][ci][co]
    // trow = local output row (t = t0-2+trow), staged x row = trow + d (abs t0-3+trow+d)
    {
        f32x4 acc1[2][4];
        #pragma unroll
        for (int n = 0; n < 4; ++n){
            float bv = b1[(wave << 6) + (n << 4) + l15];
            acc1[0][n] = f32x4{bv, bv, bv, bv};
            acc1[1][n] = f32x4{bv, bv, bv, bv};
        }
        #pragma unroll
        for (int d = 0; d < 3; ++d){
            #pragma unroll
            for (int kt = 0; kt < 3; ++kt){
                short8 ah[2], al[2];
                #pragma unroll
                for (int m = 0; m < 2; ++m){
                    int off = ((m << 4) + l15 + d)*XSTR + kt*32 + lg4*8;
                    ah[m] = __builtin_bit_cast(short8, *(const uint4*)(xhi + off));
                    al[m] = __builtin_bit_cast(short8, *(const uint4*)(xlo + off));
                }
                #pragma unroll
                for (int n = 0; n < 4; ++n){
                    int co_n = (wave << 6) + (n << 4) + l15;
                    int wo = ((((d*3 + kt)*4 + lg4) << 8) + co_n) << 3;
                    short8 bh = __builtin_bit_cast(short8, *(const uint4*)(w1fhi + wo));
                    short8 bl = __builtin_bit_cast(short8, *(const uint4*)(w1flo + wo));
                    #pragma unroll
                    for (int m = 0; m < 2; ++m){
                        acc1[m][n] = __builtin_amdgcn_mfma_f32_16x16x32_bf16(ah[m], bh, acc1[m][n], 0, 0, 0);
                        acc1[m][n] = __builtin_amdgcn_mfma_f32_16x16x32_bf16(ah[m], bl, acc1[m][n], 0, 0, 0);
                        acc1[m][n] = __builtin_amdgcn_mfma_f32_16x16x32_bf16(al[m], bh, acc1[m][n], 0, 0, 0);
                    }
                }
            }
        }
        // writeback: relu + zero-mask outside [0,T); hs[co][trow], trow<20
        #pragma unroll
        for (int m = 0; m < 2; ++m){
            #pragma unroll
            for (int n = 0; n < 4; ++n){
                int co_n = (wave << 6) + (n << 4) + l15;
                #pragma unroll
                for (int j = 0; j < 4; ++j){
                    int trow = (m << 4) + (lg4 << 2) + j;
                    if (trow < 20){
                        int t = t0 - 2 + trow;
                        float v = (t >= 0 && t < T_LEN) ? fmaxf(acc1[m][n][j], 0.f) : 0.f;
                        hs[co_n*20 + trow] = v;
                    }
                }
            }
        }
    }
    __syncthreads();

    // conv2: 18 outputs (t = t0-1+j), VALU
    float acc2[18];
    {
        float bv = b2[co];
        #pragma unroll
        for (int j = 0; j < 18; ++j) acc2[j] = bv;
        const float4* wp = W2t + co;
        float4 w = *wp;
        for (int cil = 0; cil < 32; ++cil){
            wp += 256;
            float4 wn = *wp;   // overrun lands in w3t, unused
            const float* xp = &hs[(gbase + cil)*20];
            float4 v0 = *(const float4*)(xp);
            float4 v1 = *(const float4*)(xp + 4);
            float4 v2 = *(const float4*)(xp + 8);
            float4 v3 = *(const float4*)(xp + 12);
            float4 v4 = *(const float4*)(xp + 16);
            float xr[20] = {v0.x,v0.y,v0.z,v0.w, v1.x,v1.y,v1.z,v1.w,
                            v2.x,v2.y,v2.z,v2.w, v3.x,v3.y,v3.z,v3.w,
                            v4.x,v4.y,v4.z,v4.w};
            #pragma unroll
            for (int j = 0; j < 18; ++j){
                acc2[j] = fmaf(xr[j],   w.x, acc2[j]);
                acc2[j] = fmaf(xr[j+1], w.y, acc2[j]);
                acc2[j] = fmaf(xr[j+2], w.z, acc2[j]);
            }
            w = wn;
        }
    }
    __syncthreads();
    #pragma unroll
    for (int j = 0; j < 18; ++j){
        int t = t0 - 1 + j;
        hs[co*20 + j] = (t >= 0 && t < T_LEN) ? fmaxf(acc2[j], 0.f) : 0.f;
    }
    __syncthreads();
    // conv3: 16 outputs, VALU
    float acc3[16];
    {
        float bv = b3[co];
        #pragma unroll
        for (int j = 0; j < 16; ++j) acc3[j] = bv;
        const float4* wp = W3t + co;
        float4 w = *wp;
        for (int cil = 0; cil < 32; ++cil){
            wp += 256;
            float4 wn = *wp;   // overrun lands in w1fhi, unused
            const float* xp = &hs[(gbase + cil)*20];
            float4 v0 = *(const float4*)(xp);
            float4 v1 = *(const float4*)(xp + 4);
            float4 v2 = *(const float4*)(xp + 8);
            float4 v3 = *(const float4*)(xp + 12);
            float2 v4 = *(const float2*)(xp + 16);
            float xr[18] = {v0.x,v0.y,v0.z,v0.w, v1.x,v1.y,v1.z,v1.w,
                            v2.x,v2.y,v2.z,v2.w, v3.x,v3.y,v3.z,v3.w, v4.x,v4.y};
            #pragma unroll
            for (int j = 0; j < 16; ++j){
                acc3[j] = fmaf(xr[j],   w.x, acc3[j]);
                acc3[j] = fmaf(xr[j+1], w.y, acc3[j]);
                acc3[j] = fmaf(xr[j+2], w.z, acc3[j]);
            }
            w = wn;
        }
    }
    #pragma unroll
    for (int j = 0; j < 16; ++j){
        float v = fmaxf(acc3[j], 0.f);
        __hip_bfloat16 h = __float2bfloat16(v);
        __hip_bfloat16 l = __float2bfloat16(v - __bfloat162float(h));
        size_t idx = (size_t)(b*T_LEN + t0 + j)*CCH + co;
        ohi[idx] = h;
        olo[idx] = l;
    }
}

// -------- conv4 via MFMA 16x16x32 bf16, split hi/lo (3 passes fused in K loop) --------
__global__ __launch_bounds__(256) void k_conv4(const __hip_bfloat16* __restrict__ hhi,
                                               const __hip_bfloat16* __restrict__ hlo,
                                               const __hip_bfloat16* __restrict__ wfhi,
                                               const __hip_bfloat16* __restrict__ wflo,
                                               const float* __restrict__ bias,
                                               float* __restrict__ ccep){
    __shared__ __align__(16) unsigned char aLds[2][34*512];
    const int gx = blockIdx.x;              // 400 = 16 b * 25 t-tiles
    const int b  = gx / 25;
    const int t0 = (gx - b*25) * 32;
    const int coBase = blockIdx.y << 7;     // 0 or 128
    const int tid = threadIdx.x;
    const int wave = tid >> 6;
    const int l = tid & 63;
    const int l15 = l & 15, lg = l >> 4;

    for (int i = tid; i < 2*1088; i += 256){
        int p = (i >= 1088);
        int c = i - (p ? 1088 : 0);
        int r = c >> 5, c16 = c & 31;
        int t = t0 - 1 + r;
        uint4 v = make_uint4(0u,0u,0u,0u);
        if (t >= 0 && t < T_LEN){
            const __hip_bfloat16* src = (p ? hlo : hhi) + (((size_t)(b*T_LEN + t)) << 8) + (c16 << 3);
            v = *(const uint4*)src;
        }
        int off = (r << 9) + (c16 << 4);
        off ^= (r & 7) << 4;
        *(uint4*)(&aLds[p][off]) = v;
    }
    __syncthreads();

    const int co0 = coBase + (wave << 5);
    f32x4 acc[2][2];
    #pragma unroll
    for (int n = 0; n < 2; ++n){
        int co = co0 + (n << 4) + l15;
        float bq = 0.f;
        if (co < OUT_CH){
            float q = (co < 111) ? (float)(111 - co) : (float)(co - 110);
            bq = bias[co] / q;
        }
        acc[0][n] = f32x4{bq, bq, bq, bq};
        acc[1][n] = f32x4{bq, bq, bq, bq};
    }

    for (int kt = 0; kt < 24; ++kt){
        const int d   = kt >> 3;
        const int cib = (kt & 7) << 6;
        short8 ah[2], al[2];
        #pragma unroll
        for (int m = 0; m < 2; ++m){
            int r = l15 + d + (m << 4);
            int off = (r << 9) + cib + (lg << 4);
            off ^= (r & 7) << 4;
            ah[m] = __builtin_bit_cast(short8, *(const uint4*)(&aLds[0][off]));
            al[m] = __builtin_bit_cast(short8, *(const uint4*)(&aLds[1][off]));
        }
        #pragma unroll
        for (int n = 0; n < 2; ++n){
            int co = co0 + (n << 4) + l15;
            size_t woff = ((size_t)((kt << 2) + lg) << 8) + co;
            short8 bh = __builtin_bit_cast(short8, *(const uint4*)(wfhi + (woff << 3)));
            short8 bl = __builtin_bit_cast(short8, *(const uint4*)(wflo + (woff << 3)));
            #pragma unroll
            for (int m = 0; m < 2; ++m){
                acc[m][n] = __builtin_amdgcn_mfma_f32_16x16x32_bf16(ah[m], bh, acc[m][n], 0, 0, 0);
                acc[m][n] = __builtin_amdgcn_mfma_f32_16x16x32_bf16(ah[m], bl, acc[m][n], 0, 0, 0);
                acc[m][n] = __builtin_amdgcn_mfma_f32_16x16x32_bf16(al[m], bh, acc[m][n], 0, 0, 0);
            }
        }
    }

    #pragma unroll
    for (int m = 0; m < 2; ++m){
        #pragma unroll
        for (int n = 0; n < 2; ++n){
            int co = co0 + (n << 4) + l15;
            #pragma unroll
            for (int j = 0; j < 4; ++j){
                int t = t0 + (m << 4) + (lg << 2) + j;
                ccep[((size_t)(b*T_LEN + t) << 8) + co] = acc[m][n][j];
            }
        }
    }
}

// -------- radix-4 Stockham stage; w1 from 512-entry table, w2/w3 via cmul --------
template<int N4, int Ns, bool INV, bool SKIP3>
__device__ __forceinline__ void r4s(const float2* __restrict__ src,
                                    float2* __restrict__ dst,
                                    const float2* __restrict__ Wt,
                                    int j){
    const int jm = j & (Ns - 1);
    float2 v0 = src[PHI(j)];
    float2 v1 = src[PHI(j + N4)];
    float2 v2 = src[PHI(j + 2*N4)];
    float2 v3 = make_float2(0.f, 0.f);
    if (!SKIP3) v3 = src[PHI(j + 3*N4)];
    if (Ns > 1){
        const int e = jm * (256 / Ns);   // exponent in W_1024 units
        float2 w1 = Wt[PHI(e)];
        if (INV) w1.y = -w1.y;
        float2 w2 = cmul(w1, w1);
        float2 w3 = cmul(w2, w1);
        v1 = cmul(v1, w1);
        v2 = cmul(v2, w2);
        if (!SKIP3) v3 = cmul(v3, w3);
    }
    float2 t0 = make_float2(v0.x + v2.x, v0.y + v2.y);
    float2 t1 = make_float2(v0.x - v2.x, v0.y - v2.y);
    float2 t2, t3;
    if (SKIP3){ t2 = v1; t3 = v1; }
    else {
        t2 = make_float2(v1.x + v3.x, v1.y + v3.y);
        t3 = make_float2(v1.x - v3.x, v1.y - v3.y);
    }
    float2 o0 = make_float2(t0.x + t2.x, t0.y + t2.y);
    float2 o2 = make_float2(t0.x - t2.x, t0.y - t2.y);
    float2 o1, o3;
    if (!INV){
        o1 = make_float2(t1.x + t3.y, t1.y - t3.x);
        o3 = make_float2(t1.x - t3.y, t1.y + t3.x);
    } else {
        o1 = make_float2(t1.x - t3.y, t1.y + t3.x);
        o3 = make_float2(t1.x + t3.y, t1.y - t3.x);
    }
    const int base = ((j - jm) << 2) + jm;
    dst[PHI(base)]          = o0;
    dst[PHI(base + Ns)]     = o1;
    dst[PHI(base + 2*Ns)]   = o2;
    dst[PHI(base + 3*Ns)]   = o3;
}

// -------- per-(b,t): packed fwd FFT(1024) -> merged G/Z-pack -> real-IFFT via 512 -> window --------
__global__ __launch_bounds__(256) void k_filter(const float* __restrict__ ccep,
                                                const float* __restrict__ z,
                                                float* __restrict__ zw){
    __shared__ __align__(16) float2 A[1152];
    __shared__ __align__(16) float2 Bb[1152];
    __shared__ __align__(16) float2 Wt[576];   // W_1024^k, k<512, PHI-padded
    const int t = blockIdx.x;
    const int b = blockIdx.y;
    const int tid = threadIdx.x;
    const float PI2 = 6.283185307179586f;

    for (int j = tid; j < 512; j += 256){
        float s, c;
        __sincosf(-PI2 * (float)j * (1.0f/1024.0f), &s, &c);
        Wt[PHI(j)] = make_float2(c, s);
    }
    const float* crow = &ccep[(b*T_LEN + t)*CSTRIDE];
    #pragma unroll
    for (int r = 0; r < 4; ++r){
        int i = tid + (r << 8);
        float av = (i >= 401 && i < 623) ? crow[i - 401] : 0.f;
        float fv = 0.f;
        if (i < 512){
            int zi = t*HOPSZ + i - 255;
            fv = (zi >= 0 && zi < ZLEN) ? z[b*ZLEN + zi] : 0.f;
        }
        A[PHI(i)] = make_float2(av, fv);
    }
    __syncthreads();

    r4s<256,1,  false,true >(A,  Bb, Wt, tid); __syncthreads();
    r4s<256,4,  false,false>(Bb, A,  Wt, tid); __syncthreads();
    r4s<256,16, false,false>(A,  Bb, Wt, tid); __syncthreads();
    r4s<256,64, false,false>(Bb, A,  Wt, tid); __syncthreads();
    r4s<256,256,false,false>(A,  Bb, Wt, tid); __syncthreads();

    // merged: G[k],G[512-k] -> Z'[k],Z'[512-k] written to A
    {
        const float LOG2_10_DIV10 = 0.33219280948873623f;
        auto unpackG = [&](int i)->float2 {
            float2 P = Bb[PHI(i)];
            float2 Q = Bb[PHI((1024 - i) & 1023)];
            float Are = 0.5f * (P.x + Q.x);
            float Aim = 0.5f * (P.y - Q.y);
            float Fx  = 0.5f * (P.y + Q.y);
            float Fy  = 0.5f * (Q.x - P.x);
            float mag = exp2f(Are * LOG2_10_DIV10) * (1.0f/1024.0f);
            float s, c;
            __sincosf(Aim, &s, &c);
            float Hx = mag * c, Hy = mag * s;
            return make_float2(Fx*Hx + Fy*Hy, Fx*Hy - Fy*Hx);
        };
        int k = tid;
        float2 G  = unpackG(k);
        float2 G2 = unpackG(512 - k);
        float sx = G.x + G2.x, sy = G.y - G2.y;
        float dx = G.x - G2.x, dy = G.y + G2.y;
        float2 V = Wt[PHI(k)];
        float ux = dx*V.x + dy*V.y;
        float uy = dy*V.x - dx*V.y;
        A[PHI(k)] = make_float2(sx - uy, sy + ux);
        if (k){
            A[PHI(512 - k)] = make_float2(sx + uy, ux - sy);
        } else {
            float2 G3 = unpackG(256);
            A[PHI(256)] = make_float2(2.f*G3.x, -2.f*G3.y);
        }
    }
    __syncthreads();

    if (tid < 128) r4s<128,1, true,false>(A,  Bb, Wt, tid);
    __syncthreads();
    if (tid < 128) r4s<128,4, true,false>(Bb, A,  Wt, tid);
    __syncthreads();
    if (tid < 128) r4s<128,16,true,false>(A,  Bb, Wt, tid);
    __syncthreads();
    if (tid < 128) r4s<128,64,true,false>(Bb, A,  Wt, tid);
    __syncthreads();
    {
        int j = tid;
        float2 u = A[PHI(j)];
        float2 v = A[PHI(j + 256)];
        float2 w = Wt[PHI(2*j)];
        w.y = -w.y;
        float2 vv = cmul(v, w);
        Bb[PHI(j)]       = make_float2(u.x + vv.x, u.y + vv.y);
        Bb[PHI(j + 256)] = make_float2(u.x - vv.x, u.y - vv.y);
    }
    __syncthreads();

    float* zrow = &zw[(size_t)(b*T_LEN + t)*512];
    #pragma unroll
    for (int r = 0; r < 2; ++r){
        int n = tid + (r << 8);
        int m = (511 - n) >> 1;
        float2 zv = Bb[PHI(m)];
        float yv = (n & 1) ? zv.x : zv.y;
        float wv = 0.5f * (1.0f - __cosf(PI2 * (float)n * (1.0f/512.0f)));
        zrow[n] = yv * wv;
    }
}

// -------- OLA + clip --------
__global__ __launch_bounds__(256) void k_ola(const float* __restrict__ zw,
                                             float* __restrict__ out){
    const int t = blockIdx.x;
    const int b = blockIdx.y;
    const int h = threadIdx.x;
    const int tm = (t + T_LEN - 1) % T_LEN;
    float v = zw[(size_t)(b*T_LEN + t)*512 + h]
            + zw[(size_t)(b*T_LEN + tm)*512 + 256 + h];
    v = fminf(fmaxf(v, -1.0f), 1.0f);
    out[(size_t)b*ZLEN + t*HOPSZ + h] = v;
}

extern "C" void kernel_launch(void* const* d_in, const int* in_sizes, int n_in,
                              void* d_out, int out_size, void* d_ws, size_t ws_size,
                              hipStream_t stream){
    const float* x  = (const float*)d_in[0];
    const float* z  = (const float*)d_in[1];
    const float* W1 = (const float*)d_in[2];
    const float* b1 = (const float*)d_in[3];
    const float* W2 = (const float*)d_in[4];
    const float* b2 = (const float*)d_in[5];
    const float* W3 = (const float*)d_in[6];
    const float* b3 = (const float*)d_in[7];
    const float* W4 = (const float*)d_in[8];
    const float* b4 = (const float*)d_in[9];
    float* out = (float*)d_out;
    float* ws  = (float*)d_ws;

    // layout (floats):
    float* ccep = ws;                                         // 3,276,800
    __hip_bfloat16* h3hi = (__hip_bfloat16*)(ws + 3276800);   // conv123 planes
    __hip_bfloat16* h3lo = h3hi + 3276800;
    float* zwb  = ws + 6553600;                               // 6,553,600
    // weights in FRONT of zwb (read by convs, overwritten later by k_filter)
    float4* w2t = (float4*)(zwb);                             //  8192 f4 (32768 fl)
    float4* w3t = (float4*)(zwb + 32768);                     //  8192 f4
    __hip_bfloat16* w1fhi = (__hip_bfloat16*)(zwb + 65536);   // 73728 bf16
    __hip_bfloat16* w1flo = (__hip_bfloat16*)(zwb + 102400);  // 73728 bf16
    __hip_bfloat16* wfhi  = (__hip_bfloat16*)(zwb + 139264);  // 196608 bf16
    __hip_bfloat16* wflo  = (__hip_bfloat16*)(zwb + 237568);  // ends @ 335872 fl

    dim3 blk(256);
    dim3 gwt(768, 4);
    dim3 gconv(T_LEN/16, B_SZ);       // (50,16)
    dim3 gc4(400, 2);
    dim3 gf(T_LEN, B_SZ);             // (800,16)

    k_wtrans<<<gwt, blk, 0, stream>>>(W1, W2, W3, W4, w2t, w3t, w1fhi, w1flo, wfhi, wflo);
    k_conv123<<<gconv, blk, 0, stream>>>(x, w1fhi, w1flo, b1, w2t, b2, w3t, b3, h3hi, h3lo);
    k_conv4<<<gc4, blk, 0, stream>>>(h3hi, h3lo, wfhi, wflo, b4, ccep);
    k_filter<<<gf, blk, 0, stream>>>(ccep, z, zwb);
    k_ola<<<gf, blk, 0, stream>>>(zwb, out);
}